// Round 1
// 674.909 us; speedup vs baseline: 1.0304x; 1.0304x over previous
//
#include <hip/hip_runtime.h>
#include <stdint.h>
#include <math.h>

// ---------------------------------------------------------------------------
// HippocampalFastWeight on MI355X (gfx950)
// B=8, T=2048, D=512, N=2048, K_CA3=64
// Round 8: succ GEMM ported to a 256^2-tile 8-wave phase-interleaved pipeline
// (T3+T4 counted vmcnt, T5 setprio, raw s_barrier -- no __syncthreads drain).
// BK=64 fp8 split into two 32-col halves; 4 phases per K-tile; vmcnt(2) only
// at phase1/phase3 ends. 64 KB LDS, 512 threads, grid 8x8xB = 2 clean rounds.
// gram/topk/gemm_bt unchanged (gram port is next if this verifies).
// ---------------------------------------------------------------------------

typedef __attribute__((ext_vector_type(8))) short bf16x8;
typedef __attribute__((ext_vector_type(8))) unsigned short u16x8;
typedef __attribute__((ext_vector_type(8))) unsigned char u8x8;
typedef __attribute__((ext_vector_type(4))) float f32x4;

#define GLD_LDS16(gp, lp)                                     \
  __builtin_amdgcn_global_load_lds(                           \
      (const __attribute__((address_space(1))) void*)(gp),    \
      (__attribute__((address_space(3))) void*)(lp), 16, 0, 0)

__device__ __forceinline__ uint16_t f2bf(float f) {
  uint32_t u = __float_as_uint(f);
  uint32_t r = u + 0x7FFFu + ((u >> 16) & 1u);
  return (uint16_t)(r >> 16);
}
__device__ __forceinline__ float bf2f(unsigned u) {
  return __uint_as_float(u << 16);
}

// f32 -> fp8 e4m3fn (inputs non-negative, < 448 here)
__device__ __forceinline__ uint8_t f2fp8(float f) {
#if __has_builtin(__builtin_amdgcn_cvt_pk_fp8_f32)
  return (uint8_t)(__builtin_amdgcn_cvt_pk_fp8_f32(f, 0.f, 0, false) & 0xFF);
#else
  if (!(f > 0.f)) return 0;
  if (f >= 448.f) return 0x7E;
  uint32_t u = __float_as_uint(f);
  int e = (int)((u >> 23) & 255) - 127;
  uint32_t m = u & 0x7FFFFFu;
  if (e < -6) {
    float q = f * 512.f;
    int qi = (int)(q + 0.5f);
    if (qi > 7) return 0x08;
    return (uint8_t)qi;
  }
  uint32_t keep = m >> 20;
  uint32_t rem = m & 0xFFFFFu;
  if (rem > 0x80000u || (rem == 0x80000u && (keep & 1))) keep++;
  uint32_t ee = (uint32_t)(e + 7);
  if (keep == 8) { keep = 0; ee++; }
  if (ee >= 16) return 0x7E;
  return (uint8_t)((ee << 3) | keep);
#endif
}

// bits of 64-bit mask strictly below this lane
__device__ __forceinline__ int bits_below(unsigned long long m) {
  return __builtin_amdgcn_mbcnt_hi((unsigned)(m >> 32),
                                   __builtin_amdgcn_mbcnt_lo((unsigned)m, 0));
}

// ------------------------------- cast --------------------------------------
__global__ __launch_bounds__(256) void cast_f32_bf16_k(
    const float* __restrict__ s, uint16_t* __restrict__ d, long long n) {
  long long i = (long long)blockIdx.x * 256 + threadIdx.x;
  long long stride = (long long)gridDim.x * 256;
  for (; i < n; i += stride) d[i] = f2bf(s[i]);
}

__global__ __launch_bounds__(256) void zero_f32_k(float* __restrict__ p, long long n) {
  long long i = (long long)blockIdx.x * 256 + threadIdx.x;
  if (i < n) p[i] = 0.f;
}

// ------------- transpose up_W (D x N fp32 -> N x D bf16) -------------------
__global__ __launch_bounds__(256) void transpose_upw_k(
    const float* __restrict__ src, uint16_t* __restrict__ dst, int D, int N) {
  __shared__ float t[32][33];
  int n0 = blockIdx.x * 32, d0 = blockIdx.y * 32;
  int lx = threadIdx.x & 31, ly = threadIdx.x >> 5;
#pragma unroll
  for (int r = 0; r < 4; ++r) {
    int d = d0 + ly + r * 8;
    t[ly + r * 8][lx] = src[(long long)d * N + n0 + lx];
  }
  __syncthreads();
#pragma unroll
  for (int r = 0; r < 4; ++r) {
    int n = n0 + ly + r * 8;
    dst[(long long)n * D + d0 + lx] = f2bf(t[lx][ly + r * 8]);
  }
}

// --------------------------- bf16 GEMM -------------------------------------
#define EPI_RELU_BF16 0
#define EPI_SIG 2

template <int EPI>
__global__ __launch_bounds__(256) void gemm_bt_k(
    const uint16_t* __restrict__ A, const uint16_t* __restrict__ B,
    void* __restrict__ Cv, const float* __restrict__ bias,
    int M, int N, int K) {
  __shared__ __align__(16) uint16_t As[128 * 32];
  __shared__ __align__(16) uint16_t Bs[128 * 32];
  const int tid = threadIdx.x;
  const int lane = tid & 63;
  const int wave = tid >> 6;
  const int m0 = blockIdx.x * 128;
  const int n0 = blockIdx.y * 128;
  const int wm = (wave & 1) * 64;
  const int wn = (wave >> 1) * 64;
  const int quad = lane >> 4;
  const int l16 = lane & 15;

  f32x4 acc[4][4];
#pragma unroll
  for (int i = 0; i < 4; ++i)
#pragma unroll
    for (int j = 0; j < 4; ++j) acc[i][j] = (f32x4){0.f, 0.f, 0.f, 0.f};

  const int srow = wave * 16 + (lane >> 2);
  const int sseg = lane & 3;
  const long long arow0 = (long long)(m0 + srow) * K + sseg * 8;
  const long long brow0 = (long long)(n0 + srow) * K + sseg * 8;

  for (int k0 = 0; k0 < K; k0 += 32) {
#pragma unroll
    for (int r = 0; r < 2; ++r) {
      GLD_LDS16(A + arow0 + (long long)r * 64 * K + k0,
                &As[(r * 64 + wave * 16) * 32]);
      GLD_LDS16(B + brow0 + (long long)r * 64 * K + k0,
                &Bs[(r * 64 + wave * 16) * 32]);
    }
    __syncthreads();
    bf16x8 af[4], bfr[4];
#pragma unroll
    for (int i = 0; i < 4; ++i)
      af[i] = *(const bf16x8*)(&As[(wm + i * 16 + l16) * 32 + quad * 8]);
#pragma unroll
    for (int j = 0; j < 4; ++j)
      bfr[j] = *(const bf16x8*)(&Bs[(wn + j * 16 + l16) * 32 + quad * 8]);
#pragma unroll
    for (int i = 0; i < 4; ++i)
#pragma unroll
      for (int j = 0; j < 4; ++j)
        acc[i][j] = __builtin_amdgcn_mfma_f32_16x16x32_bf16(af[i], bfr[j], acc[i][j], 0, 0, 0);
    __syncthreads();
  }

#pragma unroll
  for (int i = 0; i < 4; ++i) {
#pragma unroll
    for (int j = 0; j < 4; ++j) {
#pragma unroll
      for (int r = 0; r < 4; ++r) {
        int row = m0 + wm + i * 16 + quad * 4 + r;
        int col = n0 + wn + j * 16 + l16;
        float v = acc[i][j][r];
        if (EPI == EPI_RELU_BF16) {
          uint16_t* C = (uint16_t*)Cv;
          C[(long long)row * N + col] = f2bf(v > 0.f ? v : 0.f);
        } else {
          float* C = (float*)Cv;
          float z = v + bias[col];
          C[(long long)row * N + col] = 1.f / (1.f + __expf(-z));
        }
      }
    }
  }
}

// --------------------- fp8 Gram GEMM: G = S·S^T ----------------------------
__global__ __launch_bounds__(256) void gram_fp8_k(
    const uint8_t* __restrict__ S, uint8_t* __restrict__ G,
    long long sS, long long sG) {
  __shared__ __align__(16) uint8_t As[128 * 32];
  __shared__ __align__(16) uint8_t Bs[128 * 32];
  const int b = blockIdx.z;
  const uint8_t* Sb = S + (long long)b * sS;
  uint8_t* Gb = G + (long long)b * sG;
  int idx = blockIdx.x;
  int ti = 0;
  while ((ti + 1) * (ti + 2) / 2 <= idx) ti++;
  int tj = idx - ti * (ti + 1) / 2;
  const int m0 = ti * 128;
  const int n0 = tj * 128;
  const int tid = threadIdx.x;
  const int lane = tid & 63;
  const int wave = tid >> 6;
  const int wm = (wave & 1) * 64;
  const int wn = (wave >> 1) * 64;
  const int quad = lane >> 4;
  const int l16 = lane & 15;
  const int K = 2048, T = 2048;

  f32x4 acc[4][4];
#pragma unroll
  for (int i = 0; i < 4; ++i)
#pragma unroll
    for (int j = 0; j < 4; ++j) acc[i][j] = (f32x4){0.f, 0.f, 0.f, 0.f};

  const int srow = wave * 32 + (lane >> 1);
  const int shalf = lane & 1;
  const long long arow0 = (long long)(m0 + srow) * K + shalf * 16;
  const long long brow0 = (long long)(n0 + srow) * K + shalf * 16;

  for (int k0 = 0; k0 < K; k0 += 32) {
    GLD_LDS16(Sb + arow0 + k0, &As[wave * 1024]);
    GLD_LDS16(Sb + brow0 + k0, &Bs[wave * 1024]);
    __syncthreads();
    long af[4], bfr[4];
#pragma unroll
    for (int i = 0; i < 4; ++i)
      af[i] = *(const long*)(&As[(wm + i * 16 + l16) * 32 + quad * 8]);
#pragma unroll
    for (int j = 0; j < 4; ++j)
      bfr[j] = *(const long*)(&Bs[(wn + j * 16 + l16) * 32 + quad * 8]);
#pragma unroll
    for (int i = 0; i < 4; ++i)
#pragma unroll
      for (int j = 0; j < 4; ++j)
        acc[i][j] = __builtin_amdgcn_mfma_f32_16x16x32_fp8_fp8(af[i], bfr[j], acc[i][j], 0, 0, 0);
    __syncthreads();
  }

#pragma unroll
  for (int i = 0; i < 4; ++i) {
#pragma unroll
    for (int j = 0; j < 4; ++j) {
      uint8_t bv[4];
#pragma unroll
      for (int r = 0; r < 4; ++r) {
        int row = m0 + wm + i * 16 + quad * 4 + r;
        int col = n0 + wn + j * 16 + l16;
        uint8_t h = f2fp8(acc[i][j][r]);
        bv[r] = h;
        Gb[(long long)row * T + col] = h;
      }
      if (ti != tj) {
        int mrow = n0 + wn + j * 16 + l16;
        int mcol = m0 + wm + i * 16 + quad * 4;
        uchar4 pk = {bv[0], bv[1], bv[2], bv[3]};
        *(uchar4*)(&Gb[(long long)mrow * T + mcol]) = pk;
      }
    }
  }
}

// ---------------- fp8 succ GEMM, 256^2-tile 4-phase pipeline ---------------
// succ = relu(G @ STs^T - S*wd), in-place over S (bf16).
// 8 waves (2M x 4N), per-wave output 128x64. BK=64 fp8 as two 32-col halves.
// LDS [dbuf 2][kh 2][256 rows][32 B] per matrix = 32 KB each, 64 KB total.
// Per K-tile: 4 phases {ds_read subtile; 1 GLD round for tile t+1; s_barrier;
// setprio(1) 16 MFMA setprio(0); [vmcnt(2) at p1/p3] s_barrier}.
// Per-wave load FIFO invariant at iter entry: {A0,B0,A1,B1 of tile t} (4).
//  p1-end vmcnt(2) drains A1(t),B1(t)  -> kh1 reads at p2/p3 safe.
//  p3-end vmcnt(2) drains A0(t+1),B0(t+1) -> next iter's kh0 reads safe.
// Buffer WAR: iter t stages into dbuf c^1; c^1's previous readers finished
// before iter t-1's trailing barrier (reads complete before own MFMA lgkm).
#define MFMA16(MH)                                                             \
  __builtin_amdgcn_s_setprio(1);                                               \
  acc[(MH) * 4 + 0][0] = __builtin_amdgcn_mfma_f32_16x16x32_fp8_fp8(           \
      af0, bf0, acc[(MH) * 4 + 0][0], 0, 0, 0);                                \
  acc[(MH) * 4 + 0][1] = __builtin_amdgcn_mfma_f32_16x16x32_fp8_fp8(           \
      af0, bf1, acc[(MH) * 4 + 0][1], 0, 0, 0);                                \
  acc[(MH) * 4 + 0][2] = __builtin_amdgcn_mfma_f32_16x16x32_fp8_fp8(           \
      af0, bf2, acc[(MH) * 4 + 0][2], 0, 0, 0);                                \
  acc[(MH) * 4 + 0][3] = __builtin_amdgcn_mfma_f32_16x16x32_fp8_fp8(           \
      af0, bf3, acc[(MH) * 4 + 0][3], 0, 0, 0);                                \
  acc[(MH) * 4 + 1][0] = __builtin_amdgcn_mfma_f32_16x16x32_fp8_fp8(           \
      af1, bf0, acc[(MH) * 4 + 1][0], 0, 0, 0);                                \
  acc[(MH) * 4 + 1][1] = __builtin_amdgcn_mfma_f32_16x16x32_fp8_fp8(           \
      af1, bf1, acc[(MH) * 4 + 1][1], 0, 0, 0);                                \
  acc[(MH) * 4 + 1][2] = __builtin_amdgcn_mfma_f32_16x16x32_fp8_fp8(           \
      af1, bf2, acc[(MH) * 4 + 1][2], 0, 0, 0);                                \
  acc[(MH) * 4 + 1][3] = __builtin_amdgcn_mfma_f32_16x16x32_fp8_fp8(           \
      af1, bf3, acc[(MH) * 4 + 1][3], 0, 0, 0);                                \
  acc[(MH) * 4 + 2][0] = __builtin_amdgcn_mfma_f32_16x16x32_fp8_fp8(           \
      af2, bf0, acc[(MH) * 4 + 2][0], 0, 0, 0);                                \
  acc[(MH) * 4 + 2][1] = __builtin_amdgcn_mfma_f32_16x16x32_fp8_fp8(           \
      af2, bf1, acc[(MH) * 4 + 2][1], 0, 0, 0);                                \
  acc[(MH) * 4 + 2][2] = __builtin_amdgcn_mfma_f32_16x16x32_fp8_fp8(           \
      af2, bf2, acc[(MH) * 4 + 2][2], 0, 0, 0);                                \
  acc[(MH) * 4 + 2][3] = __builtin_amdgcn_mfma_f32_16x16x32_fp8_fp8(           \
      af2, bf3, acc[(MH) * 4 + 2][3], 0, 0, 0);                                \
  acc[(MH) * 4 + 3][0] = __builtin_amdgcn_mfma_f32_16x16x32_fp8_fp8(           \
      af3, bf0, acc[(MH) * 4 + 3][0], 0, 0, 0);                                \
  acc[(MH) * 4 + 3][1] = __builtin_amdgcn_mfma_f32_16x16x32_fp8_fp8(           \
      af3, bf1, acc[(MH) * 4 + 3][1], 0, 0, 0);                                \
  acc[(MH) * 4 + 3][2] = __builtin_amdgcn_mfma_f32_16x16x32_fp8_fp8(           \
      af3, bf2, acc[(MH) * 4 + 3][2], 0, 0, 0);                                \
  acc[(MH) * 4 + 3][3] = __builtin_amdgcn_mfma_f32_16x16x32_fp8_fp8(           \
      af3, bf3, acc[(MH) * 4 + 3][3], 0, 0, 0);                                \
  __builtin_amdgcn_s_setprio(0);

#define RD_A(KH, MH)                                                           \
  af0 = *(const long*)(la + (KH) * 8192 + ard + ((MH) * 4 + 0) * 512);         \
  af1 = *(const long*)(la + (KH) * 8192 + ard + ((MH) * 4 + 1) * 512);         \
  af2 = *(const long*)(la + (KH) * 8192 + ard + ((MH) * 4 + 2) * 512);         \
  af3 = *(const long*)(la + (KH) * 8192 + ard + ((MH) * 4 + 3) * 512);

#define RD_B(KH)                                                               \
  bf0 = *(const long*)(lb + (KH) * 8192 + brd + 0 * 512);                      \
  bf1 = *(const long*)(lb + (KH) * 8192 + brd + 1 * 512);                      \
  bf2 = *(const long*)(lb + (KH) * 8192 + brd + 2 * 512);                      \
  bf3 = *(const long*)(lb + (KH) * 8192 + brd + 3 * 512);

__global__ __launch_bounds__(512) void succ_fp8_p4_k(
    const uint8_t* __restrict__ G, const uint8_t* __restrict__ STs,
    uint16_t* __restrict__ C, const float* __restrict__ wd,
    long long sG, long long sB, long long sC) {
  __shared__ __align__(16) uint8_t LA[32768];
  __shared__ __align__(16) uint8_t LB[32768];
  const int b = blockIdx.z;
  const uint8_t* Ab = G + (long long)b * sG;
  const uint8_t* Bb = STs + (long long)b * sB;
  uint16_t* Cb = C + (long long)b * sC;
  const float* wdb = wd + (long long)b * 2048;
  const int tid = threadIdx.x;
  const int lane = tid & 63;
  const int w = tid >> 6;
  const int m0 = blockIdx.x * 256;  // blockIdx.x = M-panel -> id%8 -> XCD
  const int n0 = blockIdx.y * 256;
  const int q = lane >> 4, l16 = lane & 15;
  const int wm = (w >> 2) * 128, wn = (w & 3) * 64;
  const int K = 2048, N = 2048;

  const uint8_t* Ag = Ab + (long long)m0 * K;
  const uint8_t* Bg = Bb + (long long)n0 * K;
  // staging: wave w covers rows w*32..+31 of the 256-row tile; 2 lanes/row.
  const long long gro = (long long)(w * 32 + (lane >> 1)) * K + (lane & 1) * 16;

  // prologue: tile 0 -> dbuf 0 (order A0,B0,A1,B1 matches steady-state FIFO)
  GLD_LDS16(Ag + gro, &LA[w * 1024]);
  GLD_LDS16(Bg + gro, &LB[w * 1024]);
  GLD_LDS16(Ag + gro + 32, &LA[8192 + w * 1024]);
  GLD_LDS16(Bg + gro + 32, &LB[8192 + w * 1024]);

  f32x4 acc[8][4];
#pragma unroll
  for (int i = 0; i < 8; ++i)
#pragma unroll
    for (int j = 0; j < 4; ++j) acc[i][j] = (f32x4){0.f, 0.f, 0.f, 0.f};

  // fragment read offsets (row stride 32 B; bank-floor, no swizzle needed)
  const int ard = (wm + l16) * 32 + q * 8;
  const int brd = (wn + l16) * 32 + q * 8;

  asm volatile("s_waitcnt vmcnt(2)" ::: "memory");  // kh0 of tile 0 landed
  __builtin_amdgcn_s_barrier();

  long af0, af1, af2, af3, bf0, bf1, bf2, bf3;

  for (int t = 0; t < 31; ++t) {
    const int c = t & 1;
    const uint8_t* la = &LA[c * 16384];
    const uint8_t* lb = &LB[c * 16384];
    uint8_t* sa = &LA[(c ^ 1) * 16384];
    uint8_t* sb = &LB[(c ^ 1) * 16384];
    const long long ko = (long long)(t + 1) * 64;

    // ---- phase 0: kh0, m-frags 0..3 ----
    RD_B(0)
    RD_A(0, 0)
    GLD_LDS16(Ag + gro + ko, sa + w * 1024);
    __builtin_amdgcn_s_barrier();
    MFMA16(0)
    __builtin_amdgcn_s_barrier();

    // ---- phase 1: kh0, m-frags 4..7 ----
    RD_A(0, 1)
    GLD_LDS16(Bg + gro + ko, sb + w * 1024);
    __builtin_amdgcn_s_barrier();
    MFMA16(1)
    asm volatile("s_waitcnt vmcnt(2)" ::: "memory");  // A1(t),B1(t) landed
    __builtin_amdgcn_s_barrier();

    // ---- phase 2: kh1, m-frags 0..3 ----
    RD_B(1)
    RD_A(1, 0)
    GLD_LDS16(Ag + gro + ko + 32, sa + 8192 + w * 1024);
    __builtin_amdgcn_s_barrier();
    MFMA16(0)
    __builtin_amdgcn_s_barrier();

    // ---- phase 3: kh1, m-frags 4..7 ----
    RD_A(1, 1)
    GLD_LDS16(Bg + gro + ko + 32, sb + 8192 + w * 1024);
    __builtin_amdgcn_s_barrier();
    MFMA16(1)
    asm volatile("s_waitcnt vmcnt(2)" ::: "memory");  // A0(t+1),B0(t+1) landed
    __builtin_amdgcn_s_barrier();
  }

  {  // peeled final tile t=31 (dbuf 1), no staging
    const uint8_t* la = &LA[16384];
    const uint8_t* lb = &LB[16384];
    RD_B(0)
    RD_A(0, 0)
    __builtin_amdgcn_s_barrier();
    MFMA16(0)
    __builtin_amdgcn_s_barrier();
    RD_A(0, 1)
    __builtin_amdgcn_s_barrier();
    MFMA16(1)
    asm volatile("s_waitcnt vmcnt(0)" ::: "memory");  // A1(31),B1(31) landed
    __builtin_amdgcn_s_barrier();
    RD_B(1)
    RD_A(1, 0)
    __builtin_amdgcn_s_barrier();
    MFMA16(0)
    __builtin_amdgcn_s_barrier();
    RD_A(1, 1)
    __builtin_amdgcn_s_barrier();
    MFMA16(1)
  }

  // epilogue: v = acc - S*wd ; S <- relu(v) (bf16, in place)
#pragma unroll
  for (int i = 0; i < 8; ++i) {
#pragma unroll
    for (int j = 0; j < 4; ++j) {
#pragma unroll
      for (int r = 0; r < 4; ++r) {
        int row = m0 + wm + i * 16 + q * 4 + r;
        int col = n0 + wn + j * 16 + l16;
        long long o = (long long)row * N + col;
        float sv = bf2f(Cb[o]);
        float v = acc[i][j][r] - sv * wdb[col];
        Cb[o] = f2bf(v > 0.f ? v : 0.f);
      }
    }
  }
}

// ------- transpose+shift+wdiag: S (TxN bf16) -> STs (NxT fp8), wd ----------
__global__ __launch_bounds__(256) void transpose_shift_wd_k(
    const uint16_t* __restrict__ S, uint8_t* __restrict__ STs,
    float* __restrict__ wd, int T, int N) {
  __shared__ uint16_t tile[65][72];
  __shared__ float wdl[64];
  int t0 = blockIdx.x * 64, n0 = blockIdx.y * 64, b = blockIdx.z;
  const uint16_t* Sb = S + (long long)b * T * N;
  for (int s = threadIdx.x; s < 65 * 8; s += 256) {
    int t = s >> 3, n8 = s & 7;
    u16x8 v = (u16x8){0, 0, 0, 0, 0, 0, 0, 0};
    if (t0 + t < T) v = *(const u16x8*)(Sb + (long long)(t0 + t) * N + n0 + n8 * 8);
    *(u16x8*)(&tile[t][n8 * 8]) = v;
  }
  if (threadIdx.x < 64) wdl[threadIdx.x] = 0.f;
  __syncthreads();
  uint8_t* STsb = STs + (long long)b * N * T;
  for (int s = threadIdx.x; s < 64 * 8; s += 256) {
    int n = s >> 3, t8 = s & 7;
    u8x8 c;
    float part = 0.f;
#pragma unroll
    for (int j = 0; j < 8; ++j) {
      float a = bf2f(tile[t8 * 8 + j][n]);
      float nb = bf2f(tile[t8 * 8 + j + 1][n]);
      c[j] = f2fp8(nb);
      part = fmaf(a, nb, part);
    }
    *(u8x8*)(STsb + (long long)(n0 + n) * T + t0 + t8 * 8) = c;
    atomicAdd(&wdl[n], part);
  }
  __syncthreads();
  if (threadIdx.x < 64)
    atomicAdd(&wd[(long long)b * N + n0 + threadIdx.x], wdl[threadIdx.x]);
}

// ---------------- shared selection core (ballot binary search) -------------
struct SelInfo {
  unsigned th;
  int cg[4];    // count > th per chunk
  int tc[4];    // count == th per chunk
  int r;        // tie slots to take (64 - total greater)
  float inv;    // 1/l2norm of the selected set
};

__device__ __forceinline__ SelInfo select64(const int k_[4][8],
                                            const u16x8 v[4]) {
  unsigned lo = 0, hi = 0x7FFF;
  while (lo < hi) {
    unsigned mid = (lo + hi) >> 1;
    int cnt = 0;
#pragma unroll
    for (int c = 0; c < 4; ++c)
#pragma unroll
      for (int i = 0; i < 8; ++i)
        cnt += (int)__popcll(__ballot(k_[c][i] > (int)mid));
    if (cnt < 64) hi = mid; else lo = mid + 1;
  }
  SelInfo s;
  s.th = lo;
  const int th = (int)lo;
  int cgt = 0;
#pragma unroll
  for (int c = 0; c < 4; ++c) {
    int cg = 0, tc = 0;
#pragma unroll
    for (int i = 0; i < 8; ++i) {
      cg += (int)__popcll(__ballot(k_[c][i] > th));
      tc += (int)__popcll(__ballot(k_[c][i] == th));
    }
    s.cg[c] = cg;
    s.tc[c] = tc;
    cgt += cg;
  }
  s.r = 64 - cgt;
  float ssq = 0.f;
#pragma unroll
  for (int c = 0; c < 4; ++c)
#pragma unroll
    for (int i = 0; i < 8; ++i)
      if (k_[c][i] > th) {
        float f = bf2f((unsigned)v[c][i]);
        ssq = fmaf(f, f, ssq);
      }
#pragma unroll
  for (int off = 32; off >= 1; off >>= 1) ssq += __shfl_xor(ssq, off, 64);
  float thf = bf2f(lo);
  float sumsq = ssq + (float)s.r * thf * thf;
  s.inv = 1.f / fmaxf(sqrtf(sumsq), 1e-10f);
  return s;
}

// ---------- topk1: one wave per row, dense bf16 + fp8 outputs --------------
__global__ __launch_bounds__(256) void topk1_k(
    const uint16_t* __restrict__ H, uint16_t* __restrict__ Sbf,
    uint8_t* __restrict__ Sf8) {
  const int lane = threadIdx.x & 63;
  const int wave = threadIdx.x >> 6;
  const long long row = (long long)blockIdx.x * 4 + wave;
  const uint16_t* h = H + row * 2048;

  u16x8 v[4];
  int k_[4][8];
#pragma unroll
  for (int c = 0; c < 4; ++c) {
    v[c] = *(const u16x8*)(h + c * 512 + lane * 8);
#pragma unroll
    for (int i = 0; i < 8; ++i) k_[c][i] = (int)v[c][i];
  }
  SelInfo s = select64(k_, v);
  const int th = (int)s.th;

  int tiebase = 0;
#pragma unroll
  for (int c = 0; c < 4; ++c) {
    int B = 0;
#pragma unroll
    for (int j = 0; j < 8; ++j)
      B += bits_below(__ballot(k_[c][j] == th));
    u16x8 o16;
    u8x8 o8;
    int own = 0;
#pragma unroll
    for (int i = 0; i < 8; ++i) {
      int kv = k_[c][i];
      bool ist = (kv == th);
      bool sel = (kv > th) || (ist && (tiebase + B + own) < s.r);
      if (ist) own++;
      float nv = sel ? bf2f((unsigned)v[c][i]) * s.inv : 0.f;
      o16[i] = sel ? (unsigned short)f2bf(nv) : (unsigned short)0;
      o8[i] = sel ? f2fp8(nv) : (uint8_t)0;
    }
    *(u16x8*)(Sbf + row * 2048 + c * 512 + lane * 8) = o16;
    *(u8x8*)(Sf8 + row * 2048 + c * 512 + lane * 8) = o8;
    tiebase += s.tc[c];
  }
}

// -------- topk2 + final: one wave per row, per-wave LDS slots, gather ------
__global__ __launch_bounds__(256) void topk2_final_k(
    const uint16_t* __restrict__ H, const float* __restrict__ x,
    const float* __restrict__ g, const uint16_t* __restrict__ upTb,
    float* __restrict__ out) {
  const int lane = threadIdx.x & 63;
  const int wave = threadIdx.x >> 6;
  const long long row = (long long)blockIdx.x * 4 + wave;
  const uint16_t* h = H + row * 2048;

  __shared__ int sidx[4][64];
  __shared__ float sval[4][64];

  u16x8 v[4];
  int k_[4][8];
#pragma unroll
  for (int c = 0; c < 4; ++c) {
    v[c] = *(const u16x8*)(h + c * 512 + lane * 8);
#pragma unroll
    for (int i = 0; i < 8; ++i) k_[c][i] = (int)v[c][i];
  }
  SelInfo s = select64(k_, v);
  const int th = (int)s.th;

  int tiebase = 0;
  int cum = 0;
#pragma unroll
  for (int c = 0; c < 4; ++c) {
    int B = 0;
#pragma unroll
    for (int j = 0; j < 8; ++j)
      B += bits_below(__ballot(k_[c][j] == th));
    int own = 0;
#pragma unroll
    for (int i = 0; i < 8; ++i) {
      int kv = k_[c][i];
      bool ist = (kv == th);
      bool sel = (kv > th) || (ist && (tiebase + B + own) < s.r);
      if (ist) own++;
      unsigned long long sm = __ballot(sel);
      if (sel) {
        int slot = cum + bits_below(sm);
        sidx[wave][slot] = c * 512 + lane * 8 + i;
        sval[wave][slot] = bf2f((unsigned)v[c][i]) * s.inv;
      }
      cum += (int)__popcll(sm);
    }
    tiebase += s.tc[c];
  }
  __syncthreads();

  const int col0 = lane * 8;
  float a[8] = {0.f, 0.f, 0.f, 0.f, 0.f, 0.f, 0.f, 0.f};
#pragma unroll 4
  for (int j = 0; j < 64; ++j) {
    int idx = sidx[wave][j];
    float w = sval[wave][j];
    const u16x8 pk = *(const u16x8*)(upTb + (long long)idx * 512 + col0);
#pragma unroll
    for (int q = 0; q < 8; ++q) a[q] = fmaf(w, bf2f((unsigned)pk[q]), a[q]);
  }
  long long o = row * 512 + col0;
  const float4 xv0 = *(const float4*)(x + o);
  const float4 xv1 = *(const float4*)(x + o + 4);
  const float4 gv0 = *(const float4*)(g + o);
  const float4 gv1 = *(const float4*)(g + o + 4);
  float4 r0, r1;
  r0.x = xv0.x + gv0.x * a[0];
  r0.y = xv0.y + gv0.y * a[1];
  r0.z = xv0.z + gv0.z * a[2];
  r0.w = xv0.w + gv0.w * a[3];
  r1.x = xv1.x + gv1.x * a[4];
  r1.y = xv1.y + gv1.y * a[5];
  r1.z = xv1.z + gv1.z * a[6];
  r1.w = xv1.w + gv1.w * a[7];
  *(float4*)(out + o) = r0;
  *(float4*)(out + o + 4) = r1;
}

// ---------------------------------------------------------------------------
extern "C" void kernel_launch(void* const* d_in, const int* in_sizes, int n_in,
                              void* d_out, int out_size, void* d_ws, size_t ws_size,
                              hipStream_t stream) {
  const float* x = (const float*)d_in[0];
  const float* downW = (const float*)d_in[1];
  const float* upW = (const float*)d_in[2];
  const float* gateW = (const float*)d_in[3];
  const float* gateB = (const float*)d_in[4];
  float* out = (float*)d_out;

  const int B = 8, T = 2048, D = 512, N = 2048;
  const long long BT = (long long)B * T;
  const long long TN = (long long)T * N;
  const long long TD = (long long)T * D;

  char* base = (char*)d_ws;
  size_t off = 0;
  auto take = [&](size_t bytes) {
    size_t o = off;
    off += (bytes + 255) & ~(size_t)255;
    return o;
  };
  size_t o_xb = take((size_t)BT * D * 2);
  size_t o_dwb = take((size_t)N * D * 2);
  size_t o_gwb = take((size_t)D * D * 2);
  size_t o_upT = take((size_t)N * D * 2);
  const size_t fixed = off;
  const size_t perb = (size_t)TN * 2 + (size_t)TN * 2 + (size_t)TN +
                      (size_t)TN + (size_t)N * 4;
  int Bc = 1;
  if (ws_size >= fixed + 8 * perb) Bc = 8;
  else if (ws_size >= fixed + 4 * perb) Bc = 4;
  else if (ws_size >= fixed + 2 * perb) Bc = 2;

  uint16_t* xb = (uint16_t*)(base + o_xb);
  uint16_t* dwb = (uint16_t*)(base + o_dwb);
  uint16_t* gwb = (uint16_t*)(base + o_gwb);
  uint16_t* upTb = (uint16_t*)(base + o_upT);
  char* p = base + fixed;
  uint16_t* R1 = (uint16_t*)p; p += (size_t)TN * 2 * Bc;  // h (bf16) -> G (fp8)
  uint16_t* R2 = (uint16_t*)p; p += (size_t)TN * 2 * Bc;  // S (bf16) -> succ
  uint8_t* R3 = (uint8_t*)p;  p += (size_t)TN * Bc;       // STs fp8 -> g fp32
  uint8_t* R4 = (uint8_t*)p;  p += (size_t)TN * Bc;       // S fp8
  float* wd = (float*)p;

  cast_f32_bf16_k<<<2048, 256, 0, stream>>>(x, xb, BT * D);
  cast_f32_bf16_k<<<512, 256, 0, stream>>>(downW, dwb, (long long)N * D);
  cast_f32_bf16_k<<<128, 256, 0, stream>>>(gateW, gwb, (long long)D * D);
  transpose_upw_k<<<dim3(N / 32, D / 32), 256, 0, stream>>>(upW, upTb, D, N);

  const int ltri = 16 * 17 / 2;

  for (int b0 = 0; b0 < B; b0 += Bc) {
    const uint16_t* xc = xb + (long long)b0 * TD;
    gemm_bt_k<EPI_RELU_BF16><<<dim3(Bc * 16, 16, 1), 256, 0, stream>>>(
        xc, dwb, R1, nullptr, Bc * T, N, D);
    topk1_k<<<Bc * T / 4, 256, 0, stream>>>(R1, R2, R4);
    zero_f32_k<<<(Bc * N + 255) / 256, 256, 0, stream>>>(wd, (long long)Bc * N);
    transpose_shift_wd_k<<<dim3(T / 64, N / 64, Bc), 256, 0, stream>>>(
        R2, R3, wd, T, N);
    gram_fp8_k<<<dim3(ltri, 1, Bc), 256, 0, stream>>>(
        R4, (uint8_t*)R1, TN, (long long)T * T);
    succ_fp8_p4_k<<<dim3(8, 8, Bc), 512, 0, stream>>>(
        (const uint8_t*)R1, R3, R2, wd, (long long)T * T, TN, TN);
    gemm_bt_k<EPI_SIG><<<dim3(Bc * 16, D / 128, 1), 256, 0, stream>>>(
        xc, gwb, (float*)R3, gateB, Bc * T, D, D);
    topk2_final_k<<<Bc * T / 4, 256, 0, stream>>>(
        R2, x + (long long)b0 * TD, (const float*)R3, upTb,
        out + (long long)b0 * TD);
  }
}

// Round 2
// 568.699 us; speedup vs baseline: 1.2228x; 1.1868x over previous
//
#include <hip/hip_runtime.h>
#include <stdint.h>
#include <math.h>

// ---------------------------------------------------------------------------
// HippocampalFastWeight on MI355X (gfx950)
// B=8, T=2048, D=512, N=2048, K_CA3=64
// Round 9: fix the 4x HBM/L3 overfetch in succ+gram staging. Old staging read
// 32B per row per global_load_lds (quarter of a 128B line); panels stream
// through L2 so each line was refetched ~4x (FETCH 180MB vs 16MB working set).
// Now BK=128 fp8 = one full 128B line per row per load. Row stride 128B makes
// unswizzled ds_reads a 16-way bank conflict, so a 16B-slot XOR swizzle
// (slot ^= (row>>1)&7) is applied on BOTH sides: pre-swizzled per-lane global
// source (LDS dest stays linear for global_load_lds) + swizzled ds_read addr.
// succ keeps the 8-wave 256^2 phase pipeline (now 8 phases/iter, 16 iters,
// vmcnt(0) only at iter end, all 8 next-tile loads issued in phases 0-3).
// gram gets the same line-perfect staging with its simple 2-barrier loop.
// ---------------------------------------------------------------------------

typedef __attribute__((ext_vector_type(8))) short bf16x8;
typedef __attribute__((ext_vector_type(8))) unsigned short u16x8;
typedef __attribute__((ext_vector_type(8))) unsigned char u8x8;
typedef __attribute__((ext_vector_type(4))) float f32x4;

#define GLD_LDS16(gp, lp)                                     \
  __builtin_amdgcn_global_load_lds(                           \
      (const __attribute__((address_space(1))) void*)(gp),    \
      (__attribute__((address_space(3))) void*)(lp), 16, 0, 0)

__device__ __forceinline__ uint16_t f2bf(float f) {
  uint32_t u = __float_as_uint(f);
  uint32_t r = u + 0x7FFFu + ((u >> 16) & 1u);
  return (uint16_t)(r >> 16);
}
__device__ __forceinline__ float bf2f(unsigned u) {
  return __uint_as_float(u << 16);
}

// f32 -> fp8 e4m3fn (inputs non-negative, < 448 here)
__device__ __forceinline__ uint8_t f2fp8(float f) {
#if __has_builtin(__builtin_amdgcn_cvt_pk_fp8_f32)
  return (uint8_t)(__builtin_amdgcn_cvt_pk_fp8_f32(f, 0.f, 0, false) & 0xFF);
#else
  if (!(f > 0.f)) return 0;
  if (f >= 448.f) return 0x7E;
  uint32_t u = __float_as_uint(f);
  int e = (int)((u >> 23) & 255) - 127;
  uint32_t m = u & 0x7FFFFFu;
  if (e < -6) {
    float q = f * 512.f;
    int qi = (int)(q + 0.5f);
    if (qi > 7) return 0x08;
    return (uint8_t)qi;
  }
  uint32_t keep = m >> 20;
  uint32_t rem = m & 0xFFFFFu;
  if (rem > 0x80000u || (rem == 0x80000u && (keep & 1))) keep++;
  uint32_t ee = (uint32_t)(e + 7);
  if (keep == 8) { keep = 0; ee++; }
  if (ee >= 16) return 0x7E;
  return (uint8_t)((ee << 3) | keep);
#endif
}

// bits of 64-bit mask strictly below this lane
__device__ __forceinline__ int bits_below(unsigned long long m) {
  return __builtin_amdgcn_mbcnt_hi((unsigned)(m >> 32),
                                   __builtin_amdgcn_mbcnt_lo((unsigned)m, 0));
}

// ------------------------------- cast --------------------------------------
__global__ __launch_bounds__(256) void cast_f32_bf16_k(
    const float* __restrict__ s, uint16_t* __restrict__ d, long long n) {
  long long i = (long long)blockIdx.x * 256 + threadIdx.x;
  long long stride = (long long)gridDim.x * 256;
  for (; i < n; i += stride) d[i] = f2bf(s[i]);
}

__global__ __launch_bounds__(256) void zero_f32_k(float* __restrict__ p, long long n) {
  long long i = (long long)blockIdx.x * 256 + threadIdx.x;
  if (i < n) p[i] = 0.f;
}

// ------------- transpose up_W (D x N fp32 -> N x D bf16) -------------------
__global__ __launch_bounds__(256) void transpose_upw_k(
    const float* __restrict__ src, uint16_t* __restrict__ dst, int D, int N) {
  __shared__ float t[32][33];
  int n0 = blockIdx.x * 32, d0 = blockIdx.y * 32;
  int lx = threadIdx.x & 31, ly = threadIdx.x >> 5;
#pragma unroll
  for (int r = 0; r < 4; ++r) {
    int d = d0 + ly + r * 8;
    t[ly + r * 8][lx] = src[(long long)d * N + n0 + lx];
  }
  __syncthreads();
#pragma unroll
  for (int r = 0; r < 4; ++r) {
    int n = n0 + ly + r * 8;
    dst[(long long)n * D + d0 + lx] = f2bf(t[lx][ly + r * 8]);
  }
}

// --------------------------- bf16 GEMM -------------------------------------
#define EPI_RELU_BF16 0
#define EPI_SIG 2

template <int EPI>
__global__ __launch_bounds__(256) void gemm_bt_k(
    const uint16_t* __restrict__ A, const uint16_t* __restrict__ B,
    void* __restrict__ Cv, const float* __restrict__ bias,
    int M, int N, int K) {
  __shared__ __align__(16) uint16_t As[128 * 32];
  __shared__ __align__(16) uint16_t Bs[128 * 32];
  const int tid = threadIdx.x;
  const int lane = tid & 63;
  const int wave = tid >> 6;
  const int m0 = blockIdx.x * 128;
  const int n0 = blockIdx.y * 128;
  const int wm = (wave & 1) * 64;
  const int wn = (wave >> 1) * 64;
  const int quad = lane >> 4;
  const int l16 = lane & 15;

  f32x4 acc[4][4];
#pragma unroll
  for (int i = 0; i < 4; ++i)
#pragma unroll
    for (int j = 0; j < 4; ++j) acc[i][j] = (f32x4){0.f, 0.f, 0.f, 0.f};

  const int srow = wave * 16 + (lane >> 2);
  const int sseg = lane & 3;
  const long long arow0 = (long long)(m0 + srow) * K + sseg * 8;
  const long long brow0 = (long long)(n0 + srow) * K + sseg * 8;

  for (int k0 = 0; k0 < K; k0 += 32) {
#pragma unroll
    for (int r = 0; r < 2; ++r) {
      GLD_LDS16(A + arow0 + (long long)r * 64 * K + k0,
                &As[(r * 64 + wave * 16) * 32]);
      GLD_LDS16(B + brow0 + (long long)r * 64 * K + k0,
                &Bs[(r * 64 + wave * 16) * 32]);
    }
    __syncthreads();
    bf16x8 af[4], bfr[4];
#pragma unroll
    for (int i = 0; i < 4; ++i)
      af[i] = *(const bf16x8*)(&As[(wm + i * 16 + l16) * 32 + quad * 8]);
#pragma unroll
    for (int j = 0; j < 4; ++j)
      bfr[j] = *(const bf16x8*)(&Bs[(wn + j * 16 + l16) * 32 + quad * 8]);
#pragma unroll
    for (int i = 0; i < 4; ++i)
#pragma unroll
      for (int j = 0; j < 4; ++j)
        acc[i][j] = __builtin_amdgcn_mfma_f32_16x16x32_bf16(af[i], bfr[j], acc[i][j], 0, 0, 0);
    __syncthreads();
  }

#pragma unroll
  for (int i = 0; i < 4; ++i) {
#pragma unroll
    for (int j = 0; j < 4; ++j) {
#pragma unroll
      for (int r = 0; r < 4; ++r) {
        int row = m0 + wm + i * 16 + quad * 4 + r;
        int col = n0 + wn + j * 16 + l16;
        float v = acc[i][j][r];
        if (EPI == EPI_RELU_BF16) {
          uint16_t* C = (uint16_t*)Cv;
          C[(long long)row * N + col] = f2bf(v > 0.f ? v : 0.f);
        } else {
          float* C = (float*)Cv;
          float z = v + bias[col];
          C[(long long)row * N + col] = 1.f / (1.f + __expf(-z));
        }
      }
    }
  }
}

// --------------------- fp8 Gram GEMM: G = S·S^T ----------------------------
// BK=128 (full 128B line per row per global_load_lds). LDS row stride 128B,
// 16B-slot swizzle: LDS(row, slot s) holds global slot s ^ ((row>>1)&7).
__global__ __launch_bounds__(256) void gram_fp8_k(
    const uint8_t* __restrict__ S, uint8_t* __restrict__ G,
    long long sS, long long sG) {
  __shared__ __align__(16) uint8_t As[16384];
  __shared__ __align__(16) uint8_t Bs[16384];
  const int b = blockIdx.z;
  const uint8_t* Sb = S + (long long)b * sS;
  uint8_t* Gb = G + (long long)b * sG;
  int idx = blockIdx.x;
  int ti = 0;
  while ((ti + 1) * (ti + 2) / 2 <= idx) ti++;
  int tj = idx - ti * (ti + 1) / 2;
  const int m0 = ti * 128;
  const int n0 = tj * 128;
  const int tid = threadIdx.x;
  const int lane = tid & 63;
  const int wave = tid >> 6;
  const int wm = (wave & 1) * 64;
  const int wn = (wave >> 1) * 64;
  const int quad = lane >> 4;
  const int l16 = lane & 15;
  const int K = 2048, T = 2048;

  f32x4 acc[4][4];
#pragma unroll
  for (int i = 0; i < 4; ++i)
#pragma unroll
    for (int j = 0; j < 4; ++j) acc[i][j] = (f32x4){0.f, 0.f, 0.f, 0.f};

  // staging: round r covers rows r*32..+31; wave covers 8 rows, 8 lanes/row.
  const int srow8 = wave * 8 + (lane >> 3);                 // 0..31
  const int scol = (((lane & 7) ^ ((srow8 >> 1) & 7)) << 4);  // pre-swizzled src
  const uint8_t* Ap = Sb + (long long)m0 * K;
  const uint8_t* Bp = Sb + (long long)n0 * K;

  // fragment-read swizzle: byte = row*128 + ((slot ^ ((row>>1)&7))<<4) + (q&1)*8
  // row = w? + i*16 + l16, bases are mult-of-16 -> (row>>1)&7 = (l16>>1)&7.
  const int Xl = (l16 >> 1) & 7;
  int koff[4];
#pragma unroll
  for (int kh = 0; kh < 4; ++kh)
    koff[kh] = (((kh * 2 + (quad >> 1)) ^ Xl) << 4) + (quad & 1) * 8;
  const int ard = (wm + l16) * 128;
  const int brd = (wn + l16) * 128;

  for (int k0 = 0; k0 < K; k0 += 128) {
#pragma unroll
    for (int r = 0; r < 4; ++r) {
      GLD_LDS16(Ap + (long long)(r * 32 + srow8) * K + k0 + scol,
                &As[(r * 32 + wave * 8) * 128]);
      GLD_LDS16(Bp + (long long)(r * 32 + srow8) * K + k0 + scol,
                &Bs[(r * 32 + wave * 8) * 128]);
    }
    __syncthreads();
#pragma unroll
    for (int kh = 0; kh < 4; ++kh) {
      long af[4], bfr[4];
#pragma unroll
      for (int i = 0; i < 4; ++i)
        af[i] = *(const long*)(&As[ard + i * 2048 + koff[kh]]);
#pragma unroll
      for (int j = 0; j < 4; ++j)
        bfr[j] = *(const long*)(&Bs[brd + j * 2048 + koff[kh]]);
#pragma unroll
      for (int i = 0; i < 4; ++i)
#pragma unroll
        for (int j = 0; j < 4; ++j)
          acc[i][j] = __builtin_amdgcn_mfma_f32_16x16x32_fp8_fp8(af[i], bfr[j], acc[i][j], 0, 0, 0);
    }
    __syncthreads();
  }

#pragma unroll
  for (int i = 0; i < 4; ++i) {
#pragma unroll
    for (int j = 0; j < 4; ++j) {
      uint8_t bv[4];
#pragma unroll
      for (int r = 0; r < 4; ++r) {
        int row = m0 + wm + i * 16 + quad * 4 + r;
        int col = n0 + wn + j * 16 + l16;
        uint8_t h = f2fp8(acc[i][j][r]);
        bv[r] = h;
        Gb[(long long)row * T + col] = h;
      }
      if (ti != tj) {
        int mrow = n0 + wn + j * 16 + l16;
        int mcol = m0 + wm + i * 16 + quad * 4;
        uchar4 pk = {bv[0], bv[1], bv[2], bv[3]};
        *(uchar4*)(&Gb[(long long)mrow * T + mcol]) = pk;
      }
    }
  }
}

// ---------------- fp8 succ GEMM, 256^2-tile 8-phase pipeline ---------------
// succ = relu(G @ STs^T - S*wd), in-place over S (bf16).
// 8 waves (2M x 4N), per-wave output 128x64. BK=128 (16 K-iters).
// LDS: LA/LB = [2 dbuf][256 rows][128B] = 32KB each buf, 128KB total.
// Staging: 4 rounds per matrix per iter (64 rows each, full 128B lines),
// all 8 rounds for tile t+1 issued in phases 0-3 (2 per phase); single
// vmcnt(0)+barrier at iter end (youngest load gets ~4 phases of flight).
// Swizzle as in gram: LDS(row, slot) = global slot ^ ((row>>1)&7).
#define MFMA16(MH)                                                             \
  __builtin_amdgcn_s_setprio(1);                                               \
  acc[(MH) * 4 + 0][0] = __builtin_amdgcn_mfma_f32_16x16x32_fp8_fp8(           \
      af0, bf0, acc[(MH) * 4 + 0][0], 0, 0, 0);                                \
  acc[(MH) * 4 + 0][1] = __builtin_amdgcn_mfma_f32_16x16x32_fp8_fp8(           \
      af0, bf1, acc[(MH) * 4 + 0][1], 0, 0, 0);                                \
  acc[(MH) * 4 + 0][2] = __builtin_amdgcn_mfma_f32_16x16x32_fp8_fp8(           \
      af0, bf2, acc[(MH) * 4 + 0][2], 0, 0, 0);                                \
  acc[(MH) * 4 + 0][3] = __builtin_amdgcn_mfma_f32_16x16x32_fp8_fp8(           \
      af0, bf3, acc[(MH) * 4 + 0][3], 0, 0, 0);                                \
  acc[(MH) * 4 + 1][0] = __builtin_amdgcn_mfma_f32_16x16x32_fp8_fp8(           \
      af1, bf0, acc[(MH) * 4 + 1][0], 0, 0, 0);                                \
  acc[(MH) * 4 + 1][1] = __builtin_amdgcn_mfma_f32_16x16x32_fp8_fp8(           \
      af1, bf1, acc[(MH) * 4 + 1][1], 0, 0, 0);                                \
  acc[(MH) * 4 + 1][2] = __builtin_amdgcn_mfma_f32_16x16x32_fp8_fp8(           \
      af1, bf2, acc[(MH) * 4 + 1][2], 0, 0, 0);                                \
  acc[(MH) * 4 + 1][3] = __builtin_amdgcn_mfma_f32_16x16x32_fp8_fp8(           \
      af1, bf3, acc[(MH) * 4 + 1][3], 0, 0, 0);                                \
  acc[(MH) * 4 + 2][0] = __builtin_amdgcn_mfma_f32_16x16x32_fp8_fp8(           \
      af2, bf0, acc[(MH) * 4 + 2][0], 0, 0, 0);                                \
  acc[(MH) * 4 + 2][1] = __builtin_amdgcn_mfma_f32_16x16x32_fp8_fp8(           \
      af2, bf1, acc[(MH) * 4 + 2][1], 0, 0, 0);                                \
  acc[(MH) * 4 + 2][2] = __builtin_amdgcn_mfma_f32_16x16x32_fp8_fp8(           \
      af2, bf2, acc[(MH) * 4 + 2][2], 0, 0, 0);                                \
  acc[(MH) * 4 + 2][3] = __builtin_amdgcn_mfma_f32_16x16x32_fp8_fp8(           \
      af2, bf3, acc[(MH) * 4 + 2][3], 0, 0, 0);                                \
  acc[(MH) * 4 + 3][0] = __builtin_amdgcn_mfma_f32_16x16x32_fp8_fp8(           \
      af3, bf0, acc[(MH) * 4 + 3][0], 0, 0, 0);                                \
  acc[(MH) * 4 + 3][1] = __builtin_amdgcn_mfma_f32_16x16x32_fp8_fp8(           \
      af3, bf1, acc[(MH) * 4 + 3][1], 0, 0, 0);                                \
  acc[(MH) * 4 + 3][2] = __builtin_amdgcn_mfma_f32_16x16x32_fp8_fp8(           \
      af3, bf2, acc[(MH) * 4 + 3][2], 0, 0, 0);                                \
  acc[(MH) * 4 + 3][3] = __builtin_amdgcn_mfma_f32_16x16x32_fp8_fp8(           \
      af3, bf3, acc[(MH) * 4 + 3][3], 0, 0, 0);                                \
  __builtin_amdgcn_s_setprio(0);

#define RD_A2(KH, MH)                                                          \
  af0 = *(const long*)(la + ard + ((MH) * 4 + 0) * 2048 + koff[KH]);           \
  af1 = *(const long*)(la + ard + ((MH) * 4 + 1) * 2048 + koff[KH]);           \
  af2 = *(const long*)(la + ard + ((MH) * 4 + 2) * 2048 + koff[KH]);           \
  af3 = *(const long*)(la + ard + ((MH) * 4 + 3) * 2048 + koff[KH]);

#define RD_B2(KH)                                                              \
  bf0 = *(const long*)(lb + brd + 0 * 2048 + koff[KH]);                        \
  bf1 = *(const long*)(lb + brd + 1 * 2048 + koff[KH]);                        \
  bf2 = *(const long*)(lb + brd + 2 * 2048 + koff[KH]);                        \
  bf3 = *(const long*)(lb + brd + 3 * 2048 + koff[KH]);

#define STG_A(R)                                                               \
  GLD_LDS16(Ag + (long long)((R) * 64 + srow8) * 2048 + ko + scol,             \
            sa + ((R) * 64 + w * 8) * 128);
#define STG_B(R)                                                               \
  GLD_LDS16(Bg + (long long)((R) * 64 + srow8) * 2048 + ko + scol,             \
            sb + ((R) * 64 + w * 8) * 128);

__global__ __launch_bounds__(512) void succ_fp8_p8_k(
    const uint8_t* __restrict__ G, const uint8_t* __restrict__ STs,
    uint16_t* __restrict__ C, const float* __restrict__ wd,
    long long sG, long long sB, long long sC) {
  __shared__ __align__(16) uint8_t LA[65536];
  __shared__ __align__(16) uint8_t LB[65536];
  const int b = blockIdx.z;
  const uint8_t* Ab = G + (long long)b * sG;
  const uint8_t* Bb = STs + (long long)b * sB;
  uint16_t* Cb = C + (long long)b * sC;
  const float* wdb = wd + (long long)b * 2048;
  const int tid = threadIdx.x;
  const int lane = tid & 63;
  const int w = tid >> 6;
  const int m0 = blockIdx.x * 256;  // blockIdx.x = M-panel -> id%8 -> XCD
  const int n0 = blockIdx.y * 256;
  const int q = lane >> 4, l16 = lane & 15;
  const int wm = (w >> 2) * 128, wn = (w & 3) * 64;
  const int N = 2048;

  const uint8_t* Ag = Ab + (long long)m0 * 2048;
  const uint8_t* Bg = Bb + (long long)n0 * 2048;
  // staging: round covers 64 rows; wave covers 8 rows, 8 lanes/row (16B each).
  const int srow8 = w * 8 + (lane >> 3);                      // 0..63
  const int scol = (((lane & 7) ^ ((srow8 >> 1) & 7)) << 4);  // pre-swizzled

  // prologue: tile 0 -> dbuf 0
  {
    uint8_t* sa = &LA[0];
    uint8_t* sb = &LB[0];
    const long long ko = 0;
    STG_A(0) STG_A(1) STG_A(2) STG_A(3)
    STG_B(0) STG_B(1) STG_B(2) STG_B(3)
  }

  f32x4 acc[8][4];
#pragma unroll
  for (int i = 0; i < 8; ++i)
#pragma unroll
    for (int j = 0; j < 4; ++j) acc[i][j] = (f32x4){0.f, 0.f, 0.f, 0.f};

  const int Xl = (l16 >> 1) & 7;
  int koff[4];
#pragma unroll
  for (int kh = 0; kh < 4; ++kh)
    koff[kh] = (((kh * 2 + (q >> 1)) ^ Xl) << 4) + (q & 1) * 8;
  const int ard = (wm + l16) * 128;
  const int brd = (wn + l16) * 128;

  asm volatile("s_waitcnt vmcnt(0)" ::: "memory");
  __builtin_amdgcn_s_barrier();

  long af0, af1, af2, af3, bf0, bf1, bf2, bf3;

  for (int t = 0; t < 15; ++t) {
    const int c = t & 1;
    const uint8_t* la = &LA[c * 32768];
    const uint8_t* lb = &LB[c * 32768];
    uint8_t* sa = &LA[(c ^ 1) * 32768];
    uint8_t* sb = &LB[(c ^ 1) * 32768];
    const long long ko = (long long)(t + 1) * 128;

    // ---- phase 0: kh0 mh0 ----
    RD_B2(0) RD_A2(0, 0)
    STG_A(0) STG_A(1)
    __builtin_amdgcn_s_barrier();
    MFMA16(0)
    __builtin_amdgcn_s_barrier();
    // ---- phase 1: kh0 mh1 ----
    RD_A2(0, 1)
    STG_A(2) STG_A(3)
    __builtin_amdgcn_s_barrier();
    MFMA16(1)
    __builtin_amdgcn_s_barrier();
    // ---- phase 2: kh1 mh0 ----
    RD_B2(1) RD_A2(1, 0)
    STG_B(0) STG_B(1)
    __builtin_amdgcn_s_barrier();
    MFMA16(0)
    __builtin_amdgcn_s_barrier();
    // ---- phase 3: kh1 mh1 ----
    RD_A2(1, 1)
    STG_B(2) STG_B(3)
    __builtin_amdgcn_s_barrier();
    MFMA16(1)
    __builtin_amdgcn_s_barrier();
    // ---- phase 4: kh2 mh0 ----
    RD_B2(2) RD_A2(2, 0)
    __builtin_amdgcn_s_barrier();
    MFMA16(0)
    __builtin_amdgcn_s_barrier();
    // ---- phase 5: kh2 mh1 ----
    RD_A2(2, 1)
    __builtin_amdgcn_s_barrier();
    MFMA16(1)
    __builtin_amdgcn_s_barrier();
    // ---- phase 6: kh3 mh0 ----
    RD_B2(3) RD_A2(3, 0)
    __builtin_amdgcn_s_barrier();
    MFMA16(0)
    __builtin_amdgcn_s_barrier();
    // ---- phase 7: kh3 mh1 ----
    RD_A2(3, 1)
    __builtin_amdgcn_s_barrier();
    MFMA16(1)
    asm volatile("s_waitcnt vmcnt(0)" ::: "memory");  // tile t+1 landed
    __builtin_amdgcn_s_barrier();
  }

  {  // peeled final tile t=15 (dbuf 1), no staging
    const uint8_t* la = &LA[32768];
    const uint8_t* lb = &LB[32768];
#pragma unroll
    for (int kh = 0; kh < 4; ++kh) {
      RD_B2(kh) RD_A2(kh, 0)
      __builtin_amdgcn_s_barrier();
      MFMA16(0)
      __builtin_amdgcn_s_barrier();
      RD_A2(kh, 1)
      __builtin_amdgcn_s_barrier();
      MFMA16(1)
      if (kh < 3) __builtin_amdgcn_s_barrier();
    }
  }

  // epilogue: v = acc - S*wd ; S <- relu(v) (bf16, in place)
#pragma unroll
  for (int i = 0; i < 8; ++i) {
#pragma unroll
    for (int j = 0; j < 4; ++j) {
#pragma unroll
      for (int r = 0; r < 4; ++r) {
        int row = m0 + wm + i * 16 + q * 4 + r;
        int col = n0 + wn + j * 16 + l16;
        long long o = (long long)row * N + col;
        float sv = bf2f(Cb[o]);
        float v = acc[i][j][r] - sv * wdb[col];
        Cb[o] = f2bf(v > 0.f ? v : 0.f);
      }
    }
  }
}

// ------- transpose+shift+wdiag: S (TxN bf16) -> STs (NxT fp8), wd ----------
__global__ __launch_bounds__(256) void transpose_shift_wd_k(
    const uint16_t* __restrict__ S, uint8_t* __restrict__ STs,
    float* __restrict__ wd, int T, int N) {
  __shared__ uint16_t tile[65][72];
  __shared__ float wdl[64];
  int t0 = blockIdx.x * 64, n0 = blockIdx.y * 64, b = blockIdx.z;
  const uint16_t* Sb = S + (long long)b * T * N;
  for (int s = threadIdx.x; s < 65 * 8; s += 256) {
    int t = s >> 3, n8 = s & 7;
    u16x8 v = (u16x8){0, 0, 0, 0, 0, 0, 0, 0};
    if (t0 + t < T) v = *(const u16x8*)(Sb + (long long)(t0 + t) * N + n0 + n8 * 8);
    *(u16x8*)(&tile[t][n8 * 8]) = v;
  }
  if (threadIdx.x < 64) wdl[threadIdx.x] = 0.f;
  __syncthreads();
  uint8_t* STsb = STs + (long long)b * N * T;
  for (int s = threadIdx.x; s < 64 * 8; s += 256) {
    int n = s >> 3, t8 = s & 7;
    u8x8 c;
    float part = 0.f;
#pragma unroll
    for (int j = 0; j < 8; ++j) {
      float a = bf2f(tile[t8 * 8 + j][n]);
      float nb = bf2f(tile[t8 * 8 + j + 1][n]);
      c[j] = f2fp8(nb);
      part = fmaf(a, nb, part);
    }
    *(u8x8*)(STsb + (long long)(n0 + n) * T + t0 + t8 * 8) = c;
    atomicAdd(&wdl[n], part);
  }
  __syncthreads();
  if (threadIdx.x < 64)
    atomicAdd(&wd[(long long)b * N + n0 + threadIdx.x], wdl[threadIdx.x]);
}

// ---------------- shared selection core (ballot binary search) -------------
struct SelInfo {
  unsigned th;
  int cg[4];    // count > th per chunk
  int tc[4];    // count == th per chunk
  int r;        // tie slots to take (64 - total greater)
  float inv;    // 1/l2norm of the selected set
};

__device__ __forceinline__ SelInfo select64(const int k_[4][8],
                                            const u16x8 v[4]) {
  unsigned lo = 0, hi = 0x7FFF;
  while (lo < hi) {
    unsigned mid = (lo + hi) >> 1;
    int cnt = 0;
#pragma unroll
    for (int c = 0; c < 4; ++c)
#pragma unroll
      for (int i = 0; i < 8; ++i)
        cnt += (int)__popcll(__ballot(k_[c][i] > (int)mid));
    if (cnt < 64) hi = mid; else lo = mid + 1;
  }
  SelInfo s;
  s.th = lo;
  const int th = (int)lo;
  int cgt = 0;
#pragma unroll
  for (int c = 0; c < 4; ++c) {
    int cg = 0, tc = 0;
#pragma unroll
    for (int i = 0; i < 8; ++i) {
      cg += (int)__popcll(__ballot(k_[c][i] > th));
      tc += (int)__popcll(__ballot(k_[c][i] == th));
    }
    s.cg[c] = cg;
    s.tc[c] = tc;
    cgt += cg;
  }
  s.r = 64 - cgt;
  float ssq = 0.f;
#pragma unroll
  for (int c = 0; c < 4; ++c)
#pragma unroll
    for (int i = 0; i < 8; ++i)
      if (k_[c][i] > th) {
        float f = bf2f((unsigned)v[c][i]);
        ssq = fmaf(f, f, ssq);
      }
#pragma unroll
  for (int off = 32; off >= 1; off >>= 1) ssq += __shfl_xor(ssq, off, 64);
  float thf = bf2f(lo);
  float sumsq = ssq + (float)s.r * thf * thf;
  s.inv = 1.f / fmaxf(sqrtf(sumsq), 1e-10f);
  return s;
}

// ---------- topk1: one wave per row, dense bf16 + fp8 outputs --------------
__global__ __launch_bounds__(256) void topk1_k(
    const uint16_t* __restrict__ H, uint16_t* __restrict__ Sbf,
    uint8_t* __restrict__ Sf8) {
  const int lane = threadIdx.x & 63;
  const int wave = threadIdx.x >> 6;
  const long long row = (long long)blockIdx.x * 4 + wave;
  const uint16_t* h = H + row * 2048;

  u16x8 v[4];
  int k_[4][8];
#pragma unroll
  for (int c = 0; c < 4; ++c) {
    v[c] = *(const u16x8*)(h + c * 512 + lane * 8);
#pragma unroll
    for (int i = 0; i < 8; ++i) k_[c][i] = (int)v[c][i];
  }
  SelInfo s = select64(k_, v);
  const int th = (int)s.th;

  int tiebase = 0;
#pragma unroll
  for (int c = 0; c < 4; ++c) {
    int B = 0;
#pragma unroll
    for (int j = 0; j < 8; ++j)
      B += bits_below(__ballot(k_[c][j] == th));
    u16x8 o16;
    u8x8 o8;
    int own = 0;
#pragma unroll
    for (int i = 0; i < 8; ++i) {
      int kv = k_[c][i];
      bool ist = (kv == th);
      bool sel = (kv > th) || (ist && (tiebase + B + own) < s.r);
      if (ist) own++;
      float nv = sel ? bf2f((unsigned)v[c][i]) * s.inv : 0.f;
      o16[i] = sel ? (unsigned short)f2bf(nv) : (unsigned short)0;
      o8[i] = sel ? f2fp8(nv) : (uint8_t)0;
    }
    *(u16x8*)(Sbf + row * 2048 + c * 512 + lane * 8) = o16;
    *(u8x8*)(Sf8 + row * 2048 + c * 512 + lane * 8) = o8;
    tiebase += s.tc[c];
  }
}

// -------- topk2 + final: one wave per row, per-wave LDS slots, gather ------
__global__ __launch_bounds__(256) void topk2_final_k(
    const uint16_t* __restrict__ H, const float* __restrict__ x,
    const float* __restrict__ g, const uint16_t* __restrict__ upTb,
    float* __restrict__ out) {
  const int lane = threadIdx.x & 63;
  const int wave = threadIdx.x >> 6;
  const long long row = (long long)blockIdx.x * 4 + wave;
  const uint16_t* h = H + row * 2048;

  __shared__ int sidx[4][64];
  __shared__ float sval[4][64];

  u16x8 v[4];
  int k_[4][8];
#pragma unroll
  for (int c = 0; c < 4; ++c) {
    v[c] = *(const u16x8*)(h + c * 512 + lane * 8);
#pragma unroll
    for (int i = 0; i < 8; ++i) k_[c][i] = (int)v[c][i];
  }
  SelInfo s = select64(k_, v);
  const int th = (int)s.th;

  int tiebase = 0;
  int cum = 0;
#pragma unroll
  for (int c = 0; c < 4; ++c) {
    int B = 0;
#pragma unroll
    for (int j = 0; j < 8; ++j)
      B += bits_below(__ballot(k_[c][j] == th));
    int own = 0;
#pragma unroll
    for (int i = 0; i < 8; ++i) {
      int kv = k_[c][i];
      bool ist = (kv == th);
      bool sel = (kv > th) || (ist && (tiebase + B + own) < s.r);
      if (ist) own++;
      unsigned long long sm = __ballot(sel);
      if (sel) {
        int slot = cum + bits_below(sm);
        sidx[wave][slot] = c * 512 + lane * 8 + i;
        sval[wave][slot] = bf2f((unsigned)v[c][i]) * s.inv;
      }
      cum += (int)__popcll(sm);
    }
    tiebase += s.tc[c];
  }
  __syncthreads();

  const int col0 = lane * 8;
  float a[8] = {0.f, 0.f, 0.f, 0.f, 0.f, 0.f, 0.f, 0.f};
#pragma unroll 4
  for (int j = 0; j < 64; ++j) {
    int idx = sidx[wave][j];
    float w = sval[wave][j];
    const u16x8 pk = *(const u16x8*)(upTb + (long long)idx * 512 + col0);
#pragma unroll
    for (int q = 0; q < 8; ++q) a[q] = fmaf(w, bf2f((unsigned)pk[q]), a[q]);
  }
  long long o = row * 512 + col0;
  const float4 xv0 = *(const float4*)(x + o);
  const float4 xv1 = *(const float4*)(x + o + 4);
  const float4 gv0 = *(const float4*)(g + o);
  const float4 gv1 = *(const float4*)(g + o + 4);
  float4 r0, r1;
  r0.x = xv0.x + gv0.x * a[0];
  r0.y = xv0.y + gv0.y * a[1];
  r0.z = xv0.z + gv0.z * a[2];
  r0.w = xv0.w + gv0.w * a[3];
  r1.x = xv1.x + gv1.x * a[4];
  r1.y = xv1.y + gv1.y * a[5];
  r1.z = xv1.z + gv1.z * a[6];
  r1.w = xv1.w + gv1.w * a[7];
  *(float4*)(out + o) = r0;
  *(float4*)(out + o + 4) = r1;
}

// ---------------------------------------------------------------------------
extern "C" void kernel_launch(void* const* d_in, const int* in_sizes, int n_in,
                              void* d_out, int out_size, void* d_ws, size_t ws_size,
                              hipStream_t stream) {
  const float* x = (const float*)d_in[0];
  const float* downW = (const float*)d_in[1];
  const float* upW = (const float*)d_in[2];
  const float* gateW = (const float*)d_in[3];
  const float* gateB = (const float*)d_in[4];
  float* out = (float*)d_out;

  const int B = 8, T = 2048, D = 512, N = 2048;
  const long long BT = (long long)B * T;
  const long long TN = (long long)T * N;
  const long long TD = (long long)T * D;

  char* base = (char*)d_ws;
  size_t off = 0;
  auto take = [&](size_t bytes) {
    size_t o = off;
    off += (bytes + 255) & ~(size_t)255;
    return o;
  };
  size_t o_xb = take((size_t)BT * D * 2);
  size_t o_dwb = take((size_t)N * D * 2);
  size_t o_gwb = take((size_t)D * D * 2);
  size_t o_upT = take((size_t)N * D * 2);
  const size_t fixed = off;
  const size_t perb = (size_t)TN * 2 + (size_t)TN * 2 + (size_t)TN +
                      (size_t)TN + (size_t)N * 4;
  int Bc = 1;
  if (ws_size >= fixed + 8 * perb) Bc = 8;
  else if (ws_size >= fixed + 4 * perb) Bc = 4;
  else if (ws_size >= fixed + 2 * perb) Bc = 2;

  uint16_t* xb = (uint16_t*)(base + o_xb);
  uint16_t* dwb = (uint16_t*)(base + o_dwb);
  uint16_t* gwb = (uint16_t*)(base + o_gwb);
  uint16_t* upTb = (uint16_t*)(base + o_upT);
  char* p = base + fixed;
  uint16_t* R1 = (uint16_t*)p; p += (size_t)TN * 2 * Bc;  // h (bf16) -> G (fp8)
  uint16_t* R2 = (uint16_t*)p; p += (size_t)TN * 2 * Bc;  // S (bf16) -> succ
  uint8_t* R3 = (uint8_t*)p;  p += (size_t)TN * Bc;       // STs fp8 -> g fp32
  uint8_t* R4 = (uint8_t*)p;  p += (size_t)TN * Bc;       // S fp8
  float* wd = (float*)p;

  cast_f32_bf16_k<<<2048, 256, 0, stream>>>(x, xb, BT * D);
  cast_f32_bf16_k<<<512, 256, 0, stream>>>(downW, dwb, (long long)N * D);
  cast_f32_bf16_k<<<128, 256, 0, stream>>>(gateW, gwb, (long long)D * D);
  transpose_upw_k<<<dim3(N / 32, D / 32), 256, 0, stream>>>(upW, upTb, D, N);

  const int ltri = 16 * 17 / 2;

  for (int b0 = 0; b0 < B; b0 += Bc) {
    const uint16_t* xc = xb + (long long)b0 * TD;
    gemm_bt_k<EPI_RELU_BF16><<<dim3(Bc * 16, 16, 1), 256, 0, stream>>>(
        xc, dwb, R1, nullptr, Bc * T, N, D);
    topk1_k<<<Bc * T / 4, 256, 0, stream>>>(R1, R2, R4);
    zero_f32_k<<<(Bc * N + 255) / 256, 256, 0, stream>>>(wd, (long long)Bc * N);
    transpose_shift_wd_k<<<dim3(T / 64, N / 64, Bc), 256, 0, stream>>>(
        R2, R3, wd, T, N);
    gram_fp8_k<<<dim3(ltri, 1, Bc), 256, 0, stream>>>(
        R4, (uint8_t*)R1, TN, (long long)T * T);
    succ_fp8_p8_k<<<dim3(8, 8, Bc), 512, 0, stream>>>(
        (const uint8_t*)R1, R3, R2, wd, (long long)T * T, TN, TN);
    gemm_bt_k<EPI_SIG><<<dim3(Bc * 16, D / 128, 1), 256, 0, stream>>>(
        xc, gwb, (float*)R3, gateB, Bc * T, D, D);
    topk2_final_k<<<Bc * T / 4, 256, 0, stream>>>(
        R2, x + (long long)b0 * TD, (const float*)R3, upTb,
        out + (long long)b0 * TD);
  }
}

// Round 4
// 540.995 us; speedup vs baseline: 1.2854x; 1.0512x over previous
//
#include <hip/hip_runtime.h>
#include <stdint.h>
#include <math.h>

// ---------------------------------------------------------------------------
// HippocampalFastWeight on MI355X (gfx950)
// B=8, T=2048, D=512, N=2048, K_CA3=64
// Round 11: resubmit of round 10 (bench infra ExceptionGroup, no counters;
// kernel re-audited: uniform barriers, both-sides swizzle verified, hazard
// chain vmcnt(0)+barrier separates all LDS WAR/RAW pairs, bounds checked).
// Theory under test: 2-blocks/CU co-residency for both fp8 GEMMs.
// 256Mx128N tile, BK=64, 8 waves of 64x64 output (acc 64 VGPR), 48KB LDS,
// __launch_bounds__(512,4) -> 2 blocks/CU; cross-block TLP absorbs the
// barrier/lgkm phase gaps that the 1-block/CU r9 kernel ate raw.
// Swizzle for 64B rows: 16B-slot ^= (row>>1)&3 (both sides). gram ported to
// the same structure over the lower triangle (72 tiles/batch + mirror).
// ---------------------------------------------------------------------------

typedef __attribute__((ext_vector_type(8))) short bf16x8;
typedef __attribute__((ext_vector_type(8))) unsigned short u16x8;
typedef __attribute__((ext_vector_type(8))) unsigned char u8x8;
typedef __attribute__((ext_vector_type(4))) float f32x4;

#define GLD_LDS16(gp, lp)                                     \
  __builtin_amdgcn_global_load_lds(                           \
      (const __attribute__((address_space(1))) void*)(gp),    \
      (__attribute__((address_space(3))) void*)(lp), 16, 0, 0)

__device__ __forceinline__ uint16_t f2bf(float f) {
  uint32_t u = __float_as_uint(f);
  uint32_t r = u + 0x7FFFu + ((u >> 16) & 1u);
  return (uint16_t)(r >> 16);
}
__device__ __forceinline__ float bf2f(unsigned u) {
  return __uint_as_float(u << 16);
}

// f32 -> fp8 e4m3fn (inputs non-negative, < 448 here)
__device__ __forceinline__ uint8_t f2fp8(float f) {
#if __has_builtin(__builtin_amdgcn_cvt_pk_fp8_f32)
  return (uint8_t)(__builtin_amdgcn_cvt_pk_fp8_f32(f, 0.f, 0, false) & 0xFF);
#else
  if (!(f > 0.f)) return 0;
  if (f >= 448.f) return 0x7E;
  uint32_t u = __float_as_uint(f);
  int e = (int)((u >> 23) & 255) - 127;
  uint32_t m = u & 0x7FFFFFu;
  if (e < -6) {
    float q = f * 512.f;
    int qi = (int)(q + 0.5f);
    if (qi > 7) return 0x08;
    return (uint8_t)qi;
  }
  uint32_t keep = m >> 20;
  uint32_t rem = m & 0xFFFFFu;
  if (rem > 0x80000u || (rem == 0x80000u && (keep & 1))) keep++;
  uint32_t ee = (uint32_t)(e + 7);
  if (keep == 8) { keep = 0; ee++; }
  if (ee >= 16) return 0x7E;
  return (uint8_t)((ee << 3) | keep);
#endif
}

// bits of 64-bit mask strictly below this lane
__device__ __forceinline__ int bits_below(unsigned long long m) {
  return __builtin_amdgcn_mbcnt_hi((unsigned)(m >> 32),
                                   __builtin_amdgcn_mbcnt_lo((unsigned)m, 0));
}

// ------------------------------- cast --------------------------------------
__global__ __launch_bounds__(256) void cast_f32_bf16_k(
    const float* __restrict__ s, uint16_t* __restrict__ d, long long n) {
  long long i = (long long)blockIdx.x * 256 + threadIdx.x;
  long long stride = (long long)gridDim.x * 256;
  for (; i < n; i += stride) d[i] = f2bf(s[i]);
}

__global__ __launch_bounds__(256) void zero_f32_k(float* __restrict__ p, long long n) {
  long long i = (long long)blockIdx.x * 256 + threadIdx.x;
  if (i < n) p[i] = 0.f;
}

// ------------- transpose up_W (D x N fp32 -> N x D bf16) -------------------
__global__ __launch_bounds__(256) void transpose_upw_k(
    const float* __restrict__ src, uint16_t* __restrict__ dst, int D, int N) {
  __shared__ float t[32][33];
  int n0 = blockIdx.x * 32, d0 = blockIdx.y * 32;
  int lx = threadIdx.x & 31, ly = threadIdx.x >> 5;
#pragma unroll
  for (int r = 0; r < 4; ++r) {
    int d = d0 + ly + r * 8;
    t[ly + r * 8][lx] = src[(long long)d * N + n0 + lx];
  }
  __syncthreads();
#pragma unroll
  for (int r = 0; r < 4; ++r) {
    int n = n0 + ly + r * 8;
    dst[(long long)n * D + d0 + lx] = f2bf(t[lx][ly + r * 8]);
  }
}

// --------------------------- bf16 GEMM -------------------------------------
#define EPI_RELU_BF16 0
#define EPI_SIG 2

template <int EPI>
__global__ __launch_bounds__(256) void gemm_bt_k(
    const uint16_t* __restrict__ A, const uint16_t* __restrict__ B,
    void* __restrict__ Cv, const float* __restrict__ bias,
    int M, int N, int K) {
  __shared__ __align__(16) uint16_t As[128 * 32];
  __shared__ __align__(16) uint16_t Bs[128 * 32];
  const int tid = threadIdx.x;
  const int lane = tid & 63;
  const int wave = tid >> 6;
  const int m0 = blockIdx.x * 128;
  const int n0 = blockIdx.y * 128;
  const int wm = (wave & 1) * 64;
  const int wn = (wave >> 1) * 64;
  const int quad = lane >> 4;
  const int l16 = lane & 15;

  f32x4 acc[4][4];
#pragma unroll
  for (int i = 0; i < 4; ++i)
#pragma unroll
    for (int j = 0; j < 4; ++j) acc[i][j] = (f32x4){0.f, 0.f, 0.f, 0.f};

  const int srow = wave * 16 + (lane >> 2);
  const int sseg = lane & 3;
  const long long arow0 = (long long)(m0 + srow) * K + sseg * 8;
  const long long brow0 = (long long)(n0 + srow) * K + sseg * 8;

  for (int k0 = 0; k0 < K; k0 += 32) {
#pragma unroll
    for (int r = 0; r < 2; ++r) {
      GLD_LDS16(A + arow0 + (long long)r * 64 * K + k0,
                &As[(r * 64 + wave * 16) * 32]);
      GLD_LDS16(B + brow0 + (long long)r * 64 * K + k0,
                &Bs[(r * 64 + wave * 16) * 32]);
    }
    __syncthreads();
    bf16x8 af[4], bfr[4];
#pragma unroll
    for (int i = 0; i < 4; ++i)
      af[i] = *(const bf16x8*)(&As[(wm + i * 16 + l16) * 32 + quad * 8]);
#pragma unroll
    for (int j = 0; j < 4; ++j)
      bfr[j] = *(const bf16x8*)(&Bs[(wn + j * 16 + l16) * 32 + quad * 8]);
#pragma unroll
    for (int i = 0; i < 4; ++i)
#pragma unroll
      for (int j = 0; j < 4; ++j)
        acc[i][j] = __builtin_amdgcn_mfma_f32_16x16x32_bf16(af[i], bfr[j], acc[i][j], 0, 0, 0);
    __syncthreads();
  }

#pragma unroll
  for (int i = 0; i < 4; ++i) {
#pragma unroll
    for (int j = 0; j < 4; ++j) {
#pragma unroll
      for (int r = 0; r < 4; ++r) {
        int row = m0 + wm + i * 16 + quad * 4 + r;
        int col = n0 + wn + j * 16 + l16;
        float v = acc[i][j][r];
        if (EPI == EPI_RELU_BF16) {
          uint16_t* C = (uint16_t*)Cv;
          C[(long long)row * N + col] = f2bf(v > 0.f ? v : 0.f);
        } else {
          float* C = (float*)Cv;
          float z = v + bias[col];
          C[(long long)row * N + col] = 1.f / (1.f + __expf(-z));
        }
      }
    }
  }
}

// ----------------- shared fp8 256x128 pipelined GEMM core ------------------
// 8 waves (4M x 2N), per-wave 64x64. BK=64, 32 K-iters, double-buffered LDS:
// LA [2][256][64]=32KB, LB [2][128][64]=16KB -> 48KB -> 2 blocks/CU.
// Staging: 3 full-line GLDs/wave/iter (A rows w*32..+31 as 2, B rows
// w*16..+15 as 1), issued phase 0; vmcnt(0)+barrier at iter end.
// Swizzle (64B rows, 16B slots): LDS(r,s) = global(r, s ^ ((r>>1)&3)),
// realized by pre-swizzled global source col; readers XOR the same mask.
#define RD_AB(KH)                                                              \
  {                                                                            \
    _Pragma("unroll") for (int i = 0; i < 4; ++i) af[i] =                      \
        *(const long*)(la + ((wm + i * 16 + l16) << 6) + koff[KH]);            \
    _Pragma("unroll") for (int j = 0; j < 4; ++j) bfr[j] =                     \
        *(const long*)(lb + ((wn + j * 16 + l16) << 6) + koff[KH]);            \
  }

#define MFMA_4x4()                                                             \
  __builtin_amdgcn_s_setprio(1);                                               \
  _Pragma("unroll") for (int i = 0; i < 4; ++i)                                \
      _Pragma("unroll") for (int j = 0; j < 4; ++j) acc[i][j] =                \
          __builtin_amdgcn_mfma_f32_16x16x32_fp8_fp8(af[i], bfr[j],            \
                                                     acc[i][j], 0, 0, 0);      \
  __builtin_amdgcn_s_setprio(0);

#define STG_ALL()                                                              \
  GLD_LDS16(Ag + (long long)(w * 32 + (lane >> 2)) * 2048 + ko + sc,           \
            sa + w * 2048);                                                    \
  GLD_LDS16(Ag + (long long)(w * 32 + 16 + (lane >> 2)) * 2048 + ko + sc,      \
            sa + w * 2048 + 1024);                                             \
  GLD_LDS16(Bg + (long long)(w * 16 + (lane >> 2)) * 2048 + ko + sc,           \
            sb + w * 1024);

#define FP8_CORE_DECLS_AND_LOOP()                                              \
  const int lane = threadIdx.x & 63;                                           \
  const int w = threadIdx.x >> 6;                                              \
  const int q = lane >> 4, l16 = lane & 15;                                    \
  const int wm = (w >> 1) * 64, wn = (w & 1) * 64;                             \
  /* staging swizzle: rows gr, gr+16, B-row all share ((lane>>3)&3) mask */    \
  const int sc = (((lane & 3) ^ ((lane >> 3) & 3)) << 4);                      \
  f32x4 acc[4][4];                                                             \
  _Pragma("unroll") for (int i = 0; i < 4; ++i)                                \
      _Pragma("unroll") for (int j = 0; j < 4; ++j) acc[i][j] =                \
          (f32x4){0.f, 0.f, 0.f, 0.f};                                         \
  const int Xl = (l16 >> 1) & 3;                                               \
  int koff[2];                                                                 \
  _Pragma("unroll") for (int kh = 0; kh < 2; ++kh) koff[kh] =                  \
      (((kh * 2 + (q >> 1)) ^ Xl) << 4) + (q & 1) * 8;                         \
  {                                                                            \
    uint8_t* sa = &LA[0];                                                      \
    uint8_t* sb = &LB[0];                                                      \
    const int ko = 0;                                                          \
    STG_ALL()                                                                  \
  }                                                                            \
  asm volatile("s_waitcnt vmcnt(0)" ::: "memory");                             \
  __builtin_amdgcn_s_barrier();                                                \
  long af[4], bfr[4];                                                          \
  for (int t = 0; t < 31; ++t) {                                               \
    const int c = t & 1;                                                       \
    const uint8_t* la = &LA[c * 16384];                                        \
    const uint8_t* lb = &LB[c * 8192];                                         \
    uint8_t* sa = &LA[(c ^ 1) * 16384];                                        \
    uint8_t* sb = &LB[(c ^ 1) * 8192];                                         \
    const int ko = (t + 1) * 64;                                               \
    RD_AB(0)                                                                   \
    STG_ALL()                                                                  \
    __builtin_amdgcn_s_barrier();                                              \
    MFMA_4x4()                                                                 \
    __builtin_amdgcn_s_barrier();                                              \
    RD_AB(1)                                                                   \
    __builtin_amdgcn_s_barrier();                                              \
    MFMA_4x4()                                                                 \
    asm volatile("s_waitcnt vmcnt(0)" ::: "memory");                           \
    __builtin_amdgcn_s_barrier();                                              \
  }                                                                            \
  {                                                                            \
    const uint8_t* la = &LA[16384];                                            \
    const uint8_t* lb = &LB[8192];                                             \
    RD_AB(0)                                                                   \
    MFMA_4x4()                                                                 \
    RD_AB(1)                                                                   \
    MFMA_4x4()                                                                 \
  }

// --------------------- fp8 Gram GEMM: G = S·S^T ----------------------------
// Lower-triangle 256x128 tiles: ti in 0..7, tj in 0..2ti+1 (72/batch).
// Diagonal superblocks (tj>>1 == ti) computed fully (no mirror);
// off-diagonal tiles mirrored into the upper triangle.
__global__ __launch_bounds__(512, 4) void gram_fp8_v2_k(
    const uint8_t* __restrict__ S, uint8_t* __restrict__ G,
    long long sS, long long sG) {
  __shared__ __align__(16) uint8_t LA[32768];
  __shared__ __align__(16) uint8_t LB[16384];
  const int b = blockIdx.z;
  const uint8_t* Sb = S + (long long)b * sS;
  uint8_t* Gb = G + (long long)b * sG;
  int idx = blockIdx.x;
  int ti = 0;
  while ((ti + 1) * (ti + 2) <= idx) ti++;
  const int tj = idx - ti * (ti + 1);
  const int m0 = ti * 256;
  const int n0 = tj * 128;
  const int T = 2048;
  const uint8_t* Ag = Sb + (long long)m0 * 2048;
  const uint8_t* Bg = Sb + (long long)n0 * 2048;

  FP8_CORE_DECLS_AND_LOOP()

  const bool mirror = ((tj >> 1) != ti);
#pragma unroll
  for (int i = 0; i < 4; ++i) {
#pragma unroll
    for (int j = 0; j < 4; ++j) {
      uint8_t bv[4];
#pragma unroll
      for (int r = 0; r < 4; ++r) {
        int row = m0 + wm + i * 16 + q * 4 + r;
        int col = n0 + wn + j * 16 + l16;
        uint8_t h = f2fp8(acc[i][j][r]);
        bv[r] = h;
        Gb[(long long)row * T + col] = h;
      }
      if (mirror) {
        int mrow = n0 + wn + j * 16 + l16;
        int mcol = m0 + wm + i * 16 + q * 4;
        uchar4 pk = {bv[0], bv[1], bv[2], bv[3]};
        *(uchar4*)(&Gb[(long long)mrow * T + mcol]) = pk;
      }
    }
  }
}

// ------------------- fp8 succ GEMM: succ = relu(G@STs^T - S*wd) ------------
__global__ __launch_bounds__(512, 4) void succ_fp8_v2_k(
    const uint8_t* __restrict__ G, const uint8_t* __restrict__ STs,
    uint16_t* __restrict__ C, const float* __restrict__ wd,
    long long sG, long long sB, long long sC) {
  __shared__ __align__(16) uint8_t LA[32768];
  __shared__ __align__(16) uint8_t LB[16384];
  const int b = blockIdx.z;
  const uint8_t* Ab = G + (long long)b * sG;
  const uint8_t* Bb = STs + (long long)b * sB;
  uint16_t* Cb = C + (long long)b * sC;
  const float* wdb = wd + (long long)b * 2048;
  const int m0 = blockIdx.x * 256;  // blockIdx.x = M-panel -> id%8 -> XCD
  const int n0 = blockIdx.y * 128;
  const int N = 2048;
  const uint8_t* Ag = Ab + (long long)m0 * 2048;
  const uint8_t* Bg = Bb + (long long)n0 * 2048;

  FP8_CORE_DECLS_AND_LOOP()

  // epilogue: v = acc - S*wd ; S <- relu(v) (bf16, in place)
#pragma unroll
  for (int i = 0; i < 4; ++i) {
#pragma unroll
    for (int j = 0; j < 4; ++j) {
#pragma unroll
      for (int r = 0; r < 4; ++r) {
        int row = m0 + wm + i * 16 + q * 4 + r;
        int col = n0 + wn + j * 16 + l16;
        long long o = (long long)row * N + col;
        float sv = bf2f(Cb[o]);
        float v = acc[i][j][r] - sv * wdb[col];
        Cb[o] = f2bf(v > 0.f ? v : 0.f);
      }
    }
  }
}

// ------- transpose+shift+wdiag: S (TxN bf16) -> STs (NxT fp8), wd ----------
__global__ __launch_bounds__(256) void transpose_shift_wd_k(
    const uint16_t* __restrict__ S, uint8_t* __restrict__ STs,
    float* __restrict__ wd, int T, int N) {
  __shared__ uint16_t tile[65][72];
  __shared__ float wdl[64];
  int t0 = blockIdx.x * 64, n0 = blockIdx.y * 64, b = blockIdx.z;
  const uint16_t* Sb = S + (long long)b * T * N;
  for (int s = threadIdx.x; s < 65 * 8; s += 256) {
    int t = s >> 3, n8 = s & 7;
    u16x8 v = (u16x8){0, 0, 0, 0, 0, 0, 0, 0};
    if (t0 + t < T) v = *(const u16x8*)(Sb + (long long)(t0 + t) * N + n0 + n8 * 8);
    *(u16x8*)(&tile[t][n8 * 8]) = v;
  }
  if (threadIdx.x < 64) wdl[threadIdx.x] = 0.f;
  __syncthreads();
  uint8_t* STsb = STs + (long long)b * N * T;
  for (int s = threadIdx.x; s < 64 * 8; s += 256) {
    int n = s >> 3, t8 = s & 7;
    u8x8 c;
    float part = 0.f;
#pragma unroll
    for (int j = 0; j < 8; ++j) {
      float a = bf2f(tile[t8 * 8 + j][n]);
      float nb = bf2f(tile[t8 * 8 + j + 1][n]);
      c[j] = f2fp8(nb);
      part = fmaf(a, nb, part);
    }
    *(u8x8*)(STsb + (long long)(n0 + n) * T + t0 + t8 * 8) = c;
    atomicAdd(&wdl[n], part);
  }
  __syncthreads();
  if (threadIdx.x < 64)
    atomicAdd(&wd[(long long)b * N + n0 + threadIdx.x], wdl[threadIdx.x]);
}

// ---------------- shared selection core (ballot binary search) -------------
struct SelInfo {
  unsigned th;
  int cg[4];    // count > th per chunk
  int tc[4];    // count == th per chunk
  int r;        // tie slots to take (64 - total greater)
  float inv;    // 1/l2norm of the selected set
};

__device__ __forceinline__ SelInfo select64(const int k_[4][8],
                                            const u16x8 v[4]) {
  unsigned lo = 0, hi = 0x7FFF;
  while (lo < hi) {
    unsigned mid = (lo + hi) >> 1;
    int cnt = 0;
#pragma unroll
    for (int c = 0; c < 4; ++c)
#pragma unroll
      for (int i = 0; i < 8; ++i)
        cnt += (int)__popcll(__ballot(k_[c][i] > (int)mid));
    if (cnt < 64) hi = mid; else lo = mid + 1;
  }
  SelInfo s;
  s.th = lo;
  const int th = (int)lo;
  int cgt = 0;
#pragma unroll
  for (int c = 0; c < 4; ++c) {
    int cg = 0, tc = 0;
#pragma unroll
    for (int i = 0; i < 8; ++i) {
      cg += (int)__popcll(__ballot(k_[c][i] > th));
      tc += (int)__popcll(__ballot(k_[c][i] == th));
    }
    s.cg[c] = cg;
    s.tc[c] = tc;
    cgt += cg;
  }
  s.r = 64 - cgt;
  float ssq = 0.f;
#pragma unroll
  for (int c = 0; c < 4; ++c)
#pragma unroll
    for (int i = 0; i < 8; ++i)
      if (k_[c][i] > th) {
        float f = bf2f((unsigned)v[c][i]);
        ssq = fmaf(f, f, ssq);
      }
#pragma unroll
  for (int off = 32; off >= 1; off >>= 1) ssq += __shfl_xor(ssq, off, 64);
  float thf = bf2f(lo);
  float sumsq = ssq + (float)s.r * thf * thf;
  s.inv = 1.f / fmaxf(sqrtf(sumsq), 1e-10f);
  return s;
}

// ---------- topk1: one wave per row, dense bf16 + fp8 outputs --------------
__global__ __launch_bounds__(256) void topk1_k(
    const uint16_t* __restrict__ H, uint16_t* __restrict__ Sbf,
    uint8_t* __restrict__ Sf8) {
  const int lane = threadIdx.x & 63;
  const int wave = threadIdx.x >> 6;
  const long long row = (long long)blockIdx.x * 4 + wave;
  const uint16_t* h = H + row * 2048;

  u16x8 v[4];
  int k_[4][8];
#pragma unroll
  for (int c = 0; c < 4; ++c) {
    v[c] = *(const u16x8*)(h + c * 512 + lane * 8);
#pragma unroll
    for (int i = 0; i < 8; ++i) k_[c][i] = (int)v[c][i];
  }
  SelInfo s = select64(k_, v);
  const int th = (int)s.th;

  int tiebase = 0;
#pragma unroll
  for (int c = 0; c < 4; ++c) {
    int B = 0;
#pragma unroll
    for (int j = 0; j < 8; ++j)
      B += bits_below(__ballot(k_[c][j] == th));
    u16x8 o16;
    u8x8 o8;
    int own = 0;
#pragma unroll
    for (int i = 0; i < 8; ++i) {
      int kv = k_[c][i];
      bool ist = (kv == th);
      bool sel = (kv > th) || (ist && (tiebase + B + own) < s.r);
      if (ist) own++;
      float nv = sel ? bf2f((unsigned)v[c][i]) * s.inv : 0.f;
      o16[i] = sel ? (unsigned short)f2bf(nv) : (unsigned short)0;
      o8[i] = sel ? f2fp8(nv) : (uint8_t)0;
    }
    *(u16x8*)(Sbf + row * 2048 + c * 512 + lane * 8) = o16;
    *(u8x8*)(Sf8 + row * 2048 + c * 512 + lane * 8) = o8;
    tiebase += s.tc[c];
  }
}

// -------- topk2 + final: one wave per row, per-wave LDS slots, gather ------
__global__ __launch_bounds__(256) void topk2_final_k(
    const uint16_t* __restrict__ H, const float* __restrict__ x,
    const float* __restrict__ g, const uint16_t* __restrict__ upTb,
    float* __restrict__ out) {
  const int lane = threadIdx.x & 63;
  const int wave = threadIdx.x >> 6;
  const long long row = (long long)blockIdx.x * 4 + wave;
  const uint16_t* h = H + row * 2048;

  __shared__ int sidx[4][64];
  __shared__ float sval[4][64];

  u16x8 v[4];
  int k_[4][8];
#pragma unroll
  for (int c = 0; c < 4; ++c) {
    v[c] = *(const u16x8*)(h + c * 512 + lane * 8);
#pragma unroll
    for (int i = 0; i < 8; ++i) k_[c][i] = (int)v[c][i];
  }
  SelInfo s = select64(k_, v);
  const int th = (int)s.th;

  int tiebase = 0;
  int cum = 0;
#pragma unroll
  for (int c = 0; c < 4; ++c) {
    int B = 0;
#pragma unroll
    for (int j = 0; j < 8; ++j)
      B += bits_below(__ballot(k_[c][j] == th));
    int own = 0;
#pragma unroll
    for (int i = 0; i < 8; ++i) {
      int kv = k_[c][i];
      bool ist = (kv == th);
      bool sel = (kv > th) || (ist && (tiebase + B + own) < s.r);
      if (ist) own++;
      unsigned long long sm = __ballot(sel);
      if (sel) {
        int slot = cum + bits_below(sm);
        sidx[wave][slot] = c * 512 + lane * 8 + i;
        sval[wave][slot] = bf2f((unsigned)v[c][i]) * s.inv;
      }
      cum += (int)__popcll(sm);
    }
    tiebase += s.tc[c];
  }
  __syncthreads();

  const int col0 = lane * 8;
  float a[8] = {0.f, 0.f, 0.f, 0.f, 0.f, 0.f, 0.f, 0.f};
#pragma unroll 4
  for (int j = 0; j < 64; ++j) {
    int idx = sidx[wave][j];
    float w = sval[wave][j];
    const u16x8 pk = *(const u16x8*)(upTb + (long long)idx * 512 + col0);
#pragma unroll
    for (int q = 0; q < 8; ++q) a[q] = fmaf(w, bf2f((unsigned)pk[q]), a[q]);
  }
  long long o = row * 512 + col0;
  const float4 xv0 = *(const float4*)(x + o);
  const float4 xv1 = *(const float4*)(x + o + 4);
  const float4 gv0 = *(const float4*)(g + o);
  const float4 gv1 = *(const float4*)(g + o + 4);
  float4 r0, r1;
  r0.x = xv0.x + gv0.x * a[0];
  r0.y = xv0.y + gv0.y * a[1];
  r0.z = xv0.z + gv0.z * a[2];
  r0.w = xv0.w + gv0.w * a[3];
  r1.x = xv1.x + gv1.x * a[4];
  r1.y = xv1.y + gv1.y * a[5];
  r1.z = xv1.z + gv1.z * a[6];
  r1.w = xv1.w + gv1.w * a[7];
  *(float4*)(out + o) = r0;
  *(float4*)(out + o + 4) = r1;
}

// ---------------------------------------------------------------------------
extern "C" void kernel_launch(void* const* d_in, const int* in_sizes, int n_in,
                              void* d_out, int out_size, void* d_ws, size_t ws_size,
                              hipStream_t stream) {
  const float* x = (const float*)d_in[0];
  const float* downW = (const float*)d_in[1];
  const float* upW = (const float*)d_in[2];
  const float* gateW = (const float*)d_in[3];
  const float* gateB = (const float*)d_in[4];
  float* out = (float*)d_out;

  const int B = 8, T = 2048, D = 512, N = 2048;
  const long long BT = (long long)B * T;
  const long long TN = (long long)T * N;
  const long long TD = (long long)T * D;

  char* base = (char*)d_ws;
  size_t off = 0;
  auto take = [&](size_t bytes) {
    size_t o = off;
    off += (bytes + 255) & ~(size_t)255;
    return o;
  };
  size_t o_xb = take((size_t)BT * D * 2);
  size_t o_dwb = take((size_t)N * D * 2);
  size_t o_gwb = take((size_t)D * D * 2);
  size_t o_upT = take((size_t)N * D * 2);
  const size_t fixed = off;
  const size_t perb = (size_t)TN * 2 + (size_t)TN * 2 + (size_t)TN +
                      (size_t)TN + (size_t)N * 4;
  int Bc = 1;
  if (ws_size >= fixed + 8 * perb) Bc = 8;
  else if (ws_size >= fixed + 4 * perb) Bc = 4;
  else if (ws_size >= fixed + 2 * perb) Bc = 2;

  uint16_t* xb = (uint16_t*)(base + o_xb);
  uint16_t* dwb = (uint16_t*)(base + o_dwb);
  uint16_t* gwb = (uint16_t*)(base + o_gwb);
  uint16_t* upTb = (uint16_t*)(base + o_upT);
  char* p = base + fixed;
  uint16_t* R1 = (uint16_t*)p; p += (size_t)TN * 2 * Bc;  // h (bf16) -> G (fp8)
  uint16_t* R2 = (uint16_t*)p; p += (size_t)TN * 2 * Bc;  // S (bf16) -> succ
  uint8_t* R3 = (uint8_t*)p;  p += (size_t)TN * Bc;       // STs fp8 -> g fp32
  uint8_t* R4 = (uint8_t*)p;  p += (size_t)TN * Bc;       // S fp8
  float* wd = (float*)p;

  cast_f32_bf16_k<<<2048, 256, 0, stream>>>(x, xb, BT * D);
  cast_f32_bf16_k<<<512, 256, 0, stream>>>(downW, dwb, (long long)N * D);
  cast_f32_bf16_k<<<128, 256, 0, stream>>>(gateW, gwb, (long long)D * D);
  transpose_upw_k<<<dim3(N / 32, D / 32), 256, 0, stream>>>(upW, upTb, D, N);

  for (int b0 = 0; b0 < B; b0 += Bc) {
    const uint16_t* xc = xb + (long long)b0 * TD;
    gemm_bt_k<EPI_RELU_BF16><<<dim3(Bc * 16, 16, 1), 256, 0, stream>>>(
        xc, dwb, R1, nullptr, Bc * T, N, D);
    topk1_k<<<Bc * T / 4, 256, 0, stream>>>(R1, R2, R4);
    zero_f32_k<<<(Bc * N + 255) / 256, 256, 0, stream>>>(wd, (long long)Bc * N);
    transpose_shift_wd_k<<<dim3(T / 64, N / 64, Bc), 256, 0, stream>>>(
        R2, R3, wd, T, N);
    gram_fp8_v2_k<<<dim3(72, 1, Bc), 512, 0, stream>>>(
        R4, (uint8_t*)R1, TN, (long long)T * T);
    succ_fp8_v2_k<<<dim3(8, 16, Bc), 512, 0, stream>>>(
        (const uint8_t*)R1, R3, R2, wd, (long long)T * T, TN, TN);
    gemm_bt_k<EPI_SIG><<<dim3(Bc * 16, D / 128, 1), 256, 0, stream>>>(
        xc, gwb, (float*)R3, gateB, Bc * T, D, D);
    topk2_final_k<<<Bc * T / 4, 256, 0, stream>>>(
        R2, x + (long long)b0 * TD, (const float*)R3, upTb,
        out + (long long)b0 * TD);
  }
}